// Round 12
// baseline (165.284 us; speedup 1.0000x reference)
//
#include <hip/hip_runtime.h>
#include <hip/hip_bf16.h>

// B=8, T=512, N=64, E=128, H=256, P=96.  bn = b*64+n (512 rows).
// Identities:
//  xe = x_noD*emb  => rfft factorizes: spectral scalar s[bn,k] (packed: k<=256 real, k>256 imag)
//  mlp(s*emb) piecewise-linear in s (257 regions; tables Atab/Btab[r][e])
//  xt-part of flat@fw1:  h2[bn,h] = sum_{k,e} Yp[bn,k,e] * M2[k,e,h],
//      M2[k,(h,e)] = sum_t W[t,k] fw1[(t*128+e)*256+h]   (W = packed irfft basis)
//      Yp values are generated IN-REGISTER inside GEMM1 (fused softshrink), never materialized.
//  xn-part:   xn@F1s = hl@(tw2@F1s) + tb2@F1s,  F1s[t,h] = sum_e fw1
//  bias-part: x_noD@F1e,                        F1e[t,h] = sum_e (1+emb_e) fw1
//  s and x@F1e computed via hi/lo bf16 K-concat MFMA (A=[hi|lo|hi], B=[hi;hi;lo]) — G1 split-K.
// Round 12: k_gemm1 retiled BN=128->256 (kills the nt-duplicate cook, halves cook VALU);
//  cook conversion via __float2bfloat16 (HW cvt, not bit-twiddle).

typedef unsigned int uint;
typedef unsigned short ushort_t;
typedef __attribute__((ext_vector_type(4))) float f32x4;
typedef __attribute__((ext_vector_type(8))) short short8;

#define LAMBDA_ 0.001f
#define RSQRT512 0.044194173824159220f

__device__ __forceinline__ ushort_t f2bf(float f) {
    uint u = __float_as_uint(f);
    uint r = (u + 0x7FFFu + ((u >> 16) & 1u)) >> 16;
    return (ushort_t)r;
}
__device__ __forceinline__ ushort_t f2bf_hw(float f) {
    union { __hip_bfloat16 h; ushort_t u; } c;
    c.h = __float2bfloat16(f);
    return c.u;
}
__device__ __forceinline__ float bf2f(ushort_t v) { return __uint_as_float(((uint)v) << 16); }
__device__ __forceinline__ float leaky_(float v) { return v >= 0.f ? v : 0.01f * v; }

__device__ __forceinline__ void gload_lds16(const ushort_t* g, ushort_t* l) {
    __builtin_amdgcn_global_load_lds((const __attribute__((address_space(1))) void*)g,
                                     (__attribute__((address_space(3))) void*)l, 16, 0, 0);
}

// ---------------- K_pre: merged setup(3072) | pack_tw1(32) | transpose_x(256); grid 3360 ----------------
__global__ __launch_bounds__(256) void k_pre(const float* __restrict__ x, const float* __restrict__ tw1,
                                             const float* __restrict__ tw2,
                                             ushort_t* __restrict__ A1cat, ushort_t* __restrict__ B1cat,
                                             ushort_t* __restrict__ Wt, ushort_t* __restrict__ tw2_bf) {
    __shared__ float tile[64 * 65];
    int bid = blockIdx.x;
    int tid = threadIdx.x;
    if (bid < 3072) {
        int region = bid >> 10;
        int id = ((bid & 1023) << 8) + tid;
        int a = id >> 9, c = id & 511;
        if (region == 0) {       // B1cat rows 0-511: D[t=c][k=a], hi|hi|lo
            int f = (a <= 256) ? a : (a - 256);
            int m = (c * f) & 511;
            float ang = (float)m * (6.283185307179586f / 512.0f);
            float v = ((a <= 256) ? cosf(ang) : -sinf(ang)) * RSQRT512;
            ushort_t hi = f2bf(v);
            ushort_t lo = f2bf(v - bf2f(hi));
            size_t row = (size_t)a * 1536;
            B1cat[row + c] = hi;
            B1cat[row + 512 + c] = hi;
            B1cat[row + 1024 + c] = lo;
        } else if (region == 1) {  // Wt[k=a][t=c]
            int f = (a <= 256) ? a : (a - 256);
            int m = (c * f) & 511;
            float ang = (float)m * (6.283185307179586f / 512.0f);
            float v = ((a <= 256) ? cosf(ang) : -sinf(ang)) * RSQRT512;
            float sc = (a == 0 || a == 256) ? 1.0f : 2.0f;
            Wt[id] = f2bf(v * sc);
        } else {                   // tw2_bf (512 blocks used)
            if ((bid & 1023) < 512) tw2_bf[id] = f2bf(tw2[id]);
        }
    } else if (bid < 3104) {
        // pack_tw1 -> B1cat rows 512-767 (transposed, hi|hi|lo)
        int b = bid - 3072;               // 8 t-tiles * 4 h-tiles
        int t0 = (b & 7) << 6, h0 = (b >> 3) << 6;
        float (*t64)[65] = (float(*)[65])tile;
        for (int i = 0; i < 16; ++i) {
            int idx = tid + i * 256;
            int r = idx >> 6, cc = idx & 63;
            t64[r][cc] = tw1[(size_t)(t0 + r) * 256 + h0 + cc];
        }
        __syncthreads();
        for (int i = 0; i < 16; ++i) {
            int idx = tid + i * 256;
            int rr = idx >> 6, cc2 = idx & 63;      // rr: h, cc2: t
            float v = t64[cc2][rr];
            ushort_t hi = f2bf(v);
            ushort_t lo = f2bf(v - bf2f(hi));
            size_t row = (size_t)(512 + h0 + rr) * 1536;
            int t = t0 + cc2;
            B1cat[row + t] = hi;
            B1cat[row + 512 + t] = hi;
            B1cat[row + 1024 + t] = lo;
        }
    } else {
        // transpose_x [8][512][64] -> A1cat [512 bn][1536] (hi|lo|hi)
        int b = bid - 3104;               // 256
        int bb = b >> 5;
        int rem = b & 31;
        int t0 = (rem >> 1) << 5;
        int n0 = (rem & 1) << 5;
        int tx = tid & 31, ty = tid >> 5;
        float (*t32)[33] = (float(*)[33])tile;
        for (int i = 0; i < 4; ++i) {
            int tt = ty * 4 + i;
            t32[tt][tx] = x[(size_t)(bb * 512 + t0 + tt) * 64 + n0 + tx];
        }
        __syncthreads();
        for (int i = 0; i < 4; ++i) {
            int nn = ty * 4 + i;
            float v = t32[tx][nn];
            ushort_t hi = f2bf(v);
            ushort_t lo = f2bf(v - bf2f(hi));
            size_t row = (size_t)(bb * 64 + n0 + nn) * 1536;
            int t = t0 + tx;
            A1cat[row + t] = hi;
            A1cat[row + 512 + t] = lo;
            A1cat[row + 1024 + t] = hi;
        }
    }
}

// ---------------- K_prep1: u = emb@w1, breakpoint keys, bitonic sort (1 block) ----------------
__global__ __launch_bounds__(256) void k_prep1(const float* __restrict__ emb, const float* __restrict__ w1,
                                               const float* __restrict__ b1,
                                               float* __restrict__ u_g, int* __restrict__ idxs_g,
                                               float* __restrict__ bpkey_g) {
    __shared__ float key_s[256];
    __shared__ int idx_s[256];
    int tid = threadIdx.x;
    float acc = 0.f;
#pragma unroll 8
    for (int e = 0; e < 128; ++e) acc += emb[e] * w1[e * 256 + tid];
    u_g[tid] = acc;
    float bb0 = b1[tid];
    key_s[tid] = (acc == 0.f) ? INFINITY : (-bb0 / acc);
    idx_s[tid] = tid;
    __syncthreads();
    for (int k = 2; k <= 256; k <<= 1) {
        for (int j = k >> 1; j > 0; j >>= 1) {
            int ixj = tid ^ j;
            if (ixj > tid) {
                bool up = ((tid & k) == 0);
                float a0 = key_s[tid], a1 = key_s[ixj];
                if ((a0 > a1) == up) {
                    key_s[tid] = a1; key_s[ixj] = a0;
                    int t0 = idx_s[tid]; idx_s[tid] = idx_s[ixj]; idx_s[ixj] = t0;
                }
            }
            __syncthreads();
        }
    }
    bpkey_g[tid] = key_s[tid];
    idxs_g[tid] = idx_s[tid];
}

// ---------------- K_prep2: per-e prefix-scan table build (grid 128 = one block per e) ----------------
__global__ __launch_bounds__(256) void k_prep2(const float* __restrict__ u_g, const float* __restrict__ b1,
                                               const float* __restrict__ w2, const float* __restrict__ b2,
                                               const int* __restrict__ idxs_g,
                                               ushort_t* __restrict__ Atab, ushort_t* __restrict__ Btab) {
    __shared__ float sA[256], sB[256];
    int e = blockIdx.x, r = threadIdx.x;
    float uu0 = u_g[r], bb0 = b1[r];
    float w0 = w2[r * 128 + e];
    float c = (uu0 < 0.f || (uu0 == 0.f && bb0 >= 0.f)) ? 1.0f : 0.01f;
    float bA = c * uu0 * w0, bB = c * bb0 * w0;
    int h = idxs_g[r];
    float uu = u_g[h], bb = b1[h];
    float w = w2[h * 128 + e];
    float sgn = (uu > 0.f) ? 0.99f : -0.99f;
    float dA = sgn * uu * w, dB = sgn * bb * w;
    sA[r] = bA; sB[r] = bB;
    __syncthreads();
    for (int off = 128; off > 0; off >>= 1) {
        if (r < off) { sA[r] += sA[r + off]; sB[r] += sB[r + off]; }
        __syncthreads();
    }
    float baseA = sA[0], baseB = sB[0] + b2[e];
    __syncthreads();
    sA[r] = dA; sB[r] = dB;
    __syncthreads();
    for (int off = 1; off < 256; off <<= 1) {
        float vA = (r >= off) ? sA[r - off] : 0.f;
        float vB = (r >= off) ? sB[r - off] : 0.f;
        __syncthreads();
        sA[r] += vA; sB[r] += vB;
        __syncthreads();
    }
    if (r == 0) { Atab[e] = f2bf(baseA); Btab[e] = f2bf(baseB); }
    Atab[(r + 1) * 128 + e] = f2bf(baseA + sA[r]);
    Btab[(r + 1) * 128 + e] = f2bf(baseB + sB[r]);
}

// ---------------- K4: transpose fw1 [(t,e)][h] f32 -> fw1T[(h*128+e)][t] bf16 ----------------
__global__ __launch_bounds__(256) void k_transpose_fw1(const float* __restrict__ fw1, ushort_t* __restrict__ fw1T) {
    __shared__ float tile[64][65];
    int bid = blockIdx.x;
    int e  = bid & 127;
    int hb = (bid >> 7) & 3;
    int tt = bid >> 9;
    int t0 = tt << 6, h0 = hb << 6;
    int tid = threadIdx.x;
    for (int i = 0; i < 4; ++i) {
        int idx = tid + i * 256;            // 0..1023 float4s
        int r = idx >> 4, c4 = idx & 15;
        const float* src = fw1 + ((size_t)(t0 + r) * 128 + e) * 256 + h0 + c4 * 4;
        float4 v = *(const float4*)src;
        tile[r][c4 * 4 + 0] = v.x;
        tile[r][c4 * 4 + 1] = v.y;
        tile[r][c4 * 4 + 2] = v.z;
        tile[r][c4 * 4 + 3] = v.w;
    }
    __syncthreads();
    for (int p = 0; p < 2; ++p) {
        int idx = tid + p * 256;            // 0..511 short8s
        int hh = idx >> 3, tg = idx & 7;
        short8 o;
        for (int j = 0; j < 8; ++j) o[j] = (short)f2bf(tile[tg * 8 + j][hh]);
        *(short8*)(fw1T + ((size_t)(h0 + hh) * 128 + e) * 512 + t0 + tg * 8) = o;
    }
}

// ---------------- K4b: F1 from fw1T ----------------
__global__ __launch_bounds__(256) void k_reduce_F2(const ushort_t* __restrict__ fw1T, const float* __restrict__ emb,
                                                   float* __restrict__ F1T) {
    __shared__ float embs[128];
    int h = blockIdx.x;                  // 256
    int tid = threadIdx.x;
    if (tid < 128) embs[tid] = 1.f + emb[tid];
    __syncthreads();
    int t2 = tid * 2;
    const ushort_t* base = fw1T + ((size_t)h << 16) + t2;
    float as0 = 0.f, as1 = 0.f, ae0 = 0.f, ae1 = 0.f;
#pragma unroll 4
    for (int e = 0; e < 128; ++e) {
        uint v = *(const uint*)(base + (size_t)e * 512);
        float v0 = bf2f((ushort_t)(v & 0xffff));
        float v1 = bf2f((ushort_t)(v >> 16));
        float w = embs[e];
        as0 += v0; as1 += v1;
        ae0 += w * v0; ae1 += w * v1;
    }
    F1T[(size_t)h * 512 + t2] = as0;
    F1T[(size_t)h * 512 + t2 + 1] = as1;
    F1T[131072 + (size_t)h * 512 + t2] = ae0;
    F1T[131072 + (size_t)h * 512 + t2 + 1] = ae1;
}

// ---------------- K5: pack F1s/F1e ----------------
__global__ __launch_bounds__(64) void k_pack_F(const float* __restrict__ F1sT, const float* __restrict__ F1eT,
                                               const float* __restrict__ tb2,
                                               ushort_t* __restrict__ B1cat, ushort_t* __restrict__ F1sT_bf,
                                               float* __restrict__ p2v) {
    int h = blockIdx.x;                   // 256
    int lane = threadIdx.x;
    int t = lane * 8;
    float p2 = 0.f;
    short8 shi, ehi, elo;
    for (int j = 0; j < 8; ++j) {
        float vs = F1sT[(size_t)h * 512 + t + j];
        float ve = F1eT[(size_t)h * 512 + t + j];
        p2 += tb2[t + j] * vs;
        shi[j] = (short)f2bf(vs);
        ushort_t hi = f2bf(ve);
        ehi[j] = (short)hi;
        elo[j] = (short)f2bf(ve - bf2f(hi));
    }
    *(short8*)(F1sT_bf + (size_t)h * 512 + t) = shi;
    size_t row = (size_t)(768 + h) * 1536;
    *(short8*)(B1cat + row + t) = ehi;
    *(short8*)(B1cat + row + 512 + t) = ehi;
    *(short8*)(B1cat + row + 1024 + t) = elo;
    for (int o = 32; o > 0; o >>= 1) p2 += __shfl_xor(p2, o);
    if (lane == 0) p2v[h] = p2;
}

// ---------------- K_g1: split-K G1 partials ----------------
__global__ __launch_bounds__(256) void k_g1(const ushort_t* __restrict__ A, const ushort_t* __restrict__ Bm,
                                            float* __restrict__ partialG) {
    __shared__ ushort_t As[128 * 72];
    __shared__ ushort_t Bs[128 * 72];
    int tid = threadIdx.x;
    int lane = tid & 63, wid = tid >> 6;
    int wr = wid >> 1, wc = wid & 1;
    int bid = blockIdx.x;
    int kch = bid & 7, tilei = bid >> 3;
    int nt = tilei & 7, mt = tilei >> 3;
    int m0 = mt * 128, n0 = nt * 128;
    f32x4 acc[4][4] = {};
    for (int kt = 0; kt < 3; ++kt) {
        int kb = kch * 192 + kt * 64;
        __syncthreads();
        {
            uint4 va[4], vb[4];
            for (int i = 0; i < 4; ++i) {
                int q = tid + i * 256;
                int row = q >> 3, kcc = (q & 7) << 3;
                va[i] = *(const uint4*)(A + (size_t)(m0 + row) * 1536 + kb + kcc);
                vb[i] = *(const uint4*)(Bm + (size_t)(n0 + row) * 1536 + kb + kcc);
            }
            for (int i = 0; i < 4; ++i) {
                int q = tid + i * 256;
                int row = q >> 3, kcc = (q & 7) << 3;
                *(uint4*)&As[row * 72 + kcc] = va[i];
                *(uint4*)&Bs[row * 72 + kcc] = vb[i];
            }
        }
        __syncthreads();
        for (int ks = 0; ks < 2; ++ks) {
            short8 a[4], b[4];
            int kk = ks * 32 + (lane >> 4) * 8;
            for (int mi = 0; mi < 4; ++mi)
                a[mi] = *(const short8*)&As[(wr * 64 + mi * 16 + (lane & 15)) * 72 + kk];
            for (int ni = 0; ni < 4; ++ni)
                b[ni] = *(const short8*)&Bs[(wc * 64 + ni * 16 + (lane & 15)) * 72 + kk];
            for (int mi = 0; mi < 4; ++mi)
                for (int ni = 0; ni < 4; ++ni)
                    acc[mi][ni] = __builtin_amdgcn_mfma_f32_16x16x32_bf16(a[mi], b[ni], acc[mi][ni], 0, 0, 0);
        }
    }
    float* pbase = partialG + (size_t)kch * 524288;
    int mb0 = m0 + wr * 64 + ((lane >> 4) << 2);
    int nb0 = n0 + wc * 64 + (lane & 15);
    for (int mi = 0; mi < 4; ++mi)
        for (int ni = 0; ni < 4; ++ni) {
            int mbase = mb0 + mi * 16;
            int n = nb0 + ni * 16;
            for (int r = 0; r < 4; ++r)
                pbase[(size_t)(mbase + r) * 1024 + n] = acc[mi][ni][r];
        }
}

// ---------------- K_reduceG1 ----------------
__global__ __launch_bounds__(256) void k_reduceG1(const float* __restrict__ partialG, const float* __restrict__ tb1,
                                                  float* __restrict__ s, ushort_t* __restrict__ hl,
                                                  float* __restrict__ h2c) {
    int id = blockIdx.x * 256 + threadIdx.x;   // grid 2048 -> 524288
    int m = id >> 10, n = id & 1023;
    float acc = 0.f;
#pragma unroll
    for (int kc = 0; kc < 8; ++kc)
        acc += partialG[(size_t)kc * 524288 + id];
    if (n < 512) s[(size_t)m * 512 + n] = acc;
    else if (n < 768) hl[(size_t)m * 256 + (n - 512)] = f2bf(leaky_(acc + tb1[n - 512]));
    else h2c[(size_t)m * 256 + (n - 768)] = acc;
}

// ---------------- K_p2: P2T = (tw2 @ F1s^T)^T; grid 4 ----------------
__global__ __launch_bounds__(256) void k_p2(const ushort_t* __restrict__ A, const ushort_t* __restrict__ Bm,
                                            ushort_t* __restrict__ P2T) {
    __shared__ ushort_t As[128 * 72];
    __shared__ ushort_t Bs[128 * 72];
    int tid = threadIdx.x;
    int lane = tid & 63, wid = tid >> 6;
    int wr = wid >> 1, wc = wid & 1;
    int bid = blockIdx.x;
    int nt = bid & 1, mt = bid >> 1;
    int m0 = mt * 128, n0 = nt * 128;
    f32x4 acc[4][4] = {};
    for (int kt = 0; kt < 8; ++kt) {
        int kb = kt * 64;
        __syncthreads();
        {
            uint4 va[4], vb[4];
            for (int i = 0; i < 4; ++i) {
                int q = tid + i * 256;
                int row = q >> 3, kcc = (q & 7) << 3;
                va[i] = *(const uint4*)(A + (size_t)(m0 + row) * 512 + kb + kcc);
                vb[i] = *(const uint4*)(Bm + (size_t)(n0 + row) * 512 + kb + kcc);
            }
            for (int i = 0; i < 4; ++i) {
                int q = tid + i * 256;
                int row = q >> 3, kcc = (q & 7) << 3;
                *(uint4*)&As[row * 72 + kcc] = va[i];
                *(uint4*)&Bs[row * 72 + kcc] = vb[i];
            }
        }
        __syncthreads();
        for (int ks = 0; ks < 2; ++ks) {
            short8 a[4], b[4];
            int kk = ks * 32 + (lane >> 4) * 8;
            for (int mi = 0; mi < 4; ++mi)
                a[mi] = *(const short8*)&As[(wr * 64 + mi * 16 + (lane & 15)) * 72 + kk];
            for (int ni = 0; ni < 4; ++ni)
                b[ni] = *(const short8*)&Bs[(wc * 64 + ni * 16 + (lane & 15)) * 72 + kk];
            for (int mi = 0; mi < 4; ++mi)
                for (int ni = 0; ni < 4; ++ni)
                    acc[mi][ni] = __builtin_amdgcn_mfma_f32_16x16x32_bf16(a[mi], b[ni], acc[mi][ni], 0, 0, 0);
        }
    }
    int mb0 = m0 + wr * 64 + ((lane >> 4) << 2);
    int nb0 = n0 + wc * 64 + (lane & 15);
    for (int mi = 0; mi < 4; ++mi)
        for (int ni = 0; ni < 4; ++ni) {
            int mbase = mb0 + mi * 16;
            int n = nb0 + ni * 16;
            ushort4 o;
            o.x = f2bf(acc[mi][ni][0]);
            o.y = f2bf(acc[mi][ni][1]);
            o.z = f2bf(acc[mi][ni][2]);
            o.w = f2bf(acc[mi][ni][3]);
            *(ushort4*)(P2T + (size_t)n * 256 + mbase) = o;
        }
}

// ---------------- GEMM0: M2T = Wt @ fw1T^T (M=512, N=32768, K=512) ----------------
__global__ __launch_bounds__(512) void k_gemm0(const ushort_t* __restrict__ A, const ushort_t* __restrict__ Bm,
                                               ushort_t* __restrict__ M2T) {
    __shared__ ushort_t As[2][128 * 64];
    __shared__ ushort_t Bs[2][128 * 64];
    int tid = threadIdx.x;
    int lane = tid & 63, wid = tid >> 6;
    int wr = wid >> 2, wc = wid & 3;          // 2 x 4 waves; wave tile 64m x 32n
    int bid = blockIdx.x;
    int xx = bid & 7, y = bid >> 3;
    int mt = y & 3;
    int nt = ((y >> 2) << 3) | xx;
    int m0 = mt * 128, n0 = nt * 128;
    int lrow = lane >> 3;                     // 0..7
    int sg = (lane & 7) ^ lrow;               // swizzled source 16B-slot
    auto issue = [&](int kt, int buf) {
        int kb = kt * 64;
        for (int i = 0; i < 2; ++i) {
            int rbase = wid * 16 + i * 8;
            gload_lds16(A + (size_t)(m0 + rbase + lrow) * 512 + kb + sg * 8, &As[buf][wid * 1024 + i * 512]);
            gload_lds16(Bm + (size_t)(n0 + rbase + lrow) * 512 + kb + sg * 8, &Bs[buf][wid * 1024 + i * 512]);
        }
    };
    f32x4 acc[4][2] = {};
    issue(0, 0);
    __syncthreads();
    int cur = 0;
    for (int kt = 0; kt < 8; ++kt) {
        int nxt = cur ^ 1;
        if (kt + 1 < 8) issue(kt + 1, nxt);
        __builtin_amdgcn_s_setprio(1);
        for (int ks = 0; ks < 2; ++ks) {
            short8 a[4], b[2];
            int sl = ks * 4 + (lane >> 4);
            for (int mi = 0; mi < 4; ++mi) {
                int row = wr * 64 + mi * 16 + (lane & 15);
                a[mi] = *(const short8*)&As[cur][row * 64 + ((sl ^ (row & 7)) << 3)];
            }
            for (int ni = 0; ni < 2; ++ni) {
                int row = wc * 32 + ni * 16 + (lane & 15);
                b[ni] = *(const short8*)&Bs[cur][row * 64 + ((sl ^ (row & 7)) << 3)];
            }
            for (int mi = 0; mi < 4; ++mi)
                for (int ni = 0; ni < 2; ++ni)
                    acc[mi][ni] = __builtin_amdgcn_mfma_f32_16x16x32_bf16(a[mi], b[ni], acc[mi][ni], 0, 0, 0);
        }
        __builtin_amdgcn_s_setprio(0);
        __syncthreads();
        cur = nxt;
    }
    ushort_t* cstage = &As[0][0];
    for (int mi = 0; mi < 4; ++mi) {
        int ml = wr * 64 + mi * 16 + ((lane >> 4) << 2);
        for (int ni = 0; ni < 2; ++ni) {
            int nl = wc * 32 + ni * 16 + (lane & 15);
            for (int r = 0; r < 4; ++r) {
                int row = ml + r;
                cstage[row * 128 + (nl ^ ((row & 7) << 4))] = f2bf(acc[mi][ni][r]);
            }
        }
    }
    __syncthreads();
    short8* d8 = (short8*)(M2T + ((size_t)(n0 >> 7) << 16) + (size_t)m0 * 128);
    for (int i = 0; i < 4; ++i) {
        int p = tid + i * 512;
        int row = p >> 4;
        int col0 = (p & 15) * 8;
        d8[p] = *(const short8*)&cstage[row * 128 + (col0 ^ ((row & 7) << 4))];
    }
}

// ---------------- GEMM1 (fused): partial[kc] = cook(s) @ M2T^T chunk ----------------
// M=512, N=256 (FULL N per block), K=65536. BM=128, BN=256, split-K 64 chunks of 1024.
// grid 256 = xcd(8) x [kcl(8) x mt(4)]; one block/CU, 8 waves 2x4 (wave tile 64x64).
// B via global_load_lds (swizzled source, dbuf); A cooked in-register -> swizzled ds_write.
__global__ __launch_bounds__(512) void k_gemm1(const float* __restrict__ s,
                                               const ushort_t* __restrict__ Atab, const ushort_t* __restrict__ Btab,
                                               const float* __restrict__ bpkey,
                                               const ushort_t* __restrict__ Bm,
                                               float* __restrict__ partial) {
    __shared__ ushort_t As[2][128 * 64];     // 32 KB
    __shared__ ushort_t Bs[2][256 * 64];     // 64 KB
    __shared__ float sv_s[1024];
    __shared__ ushort_t r_s[1024];
    __shared__ float bp_s[256];
    int tid = threadIdx.x;
    int lane = tid & 63, wid = tid >> 6;
    int wr = wid >> 2, wc = wid & 3;           // 2 x 4 waves; wave tile 64m x 64n
    int bid = blockIdx.x;
    int xcd = bid & 7, j = bid >> 3;           // j: 0..31
    int kcl = j & 7, mt = j >> 3;              // mt 0..3
    int kc = xcd * 8 + kcl;                    // 0..63
    int m0 = mt * 128;
    int k0 = kc * 1024;
    if (tid < 256) bp_s[tid] = bpkey[tid];
    __syncthreads();
    {   // stage s-slice (128 rows x 8 k) + region lookup: 512 thr x float2
        int row = tid >> 2, j2 = (tid & 3) * 2;
        float2 sv2 = *(const float2*)(s + (size_t)(m0 + row) * 512 + kc * 8 + j2);
        float svv[2] = {sv2.x, sv2.y};
        for (int q = 0; q < 2; ++q) {
            float sv = svv[q];
            int lo = 0, hi = 256;
            while (lo < hi) { int mid = (lo + hi) >> 1; if (bp_s[mid] <= sv) lo = mid + 1; else hi = mid; }
            sv_s[row * 8 + j2 + q] = sv;
            r_s[row * 8 + j2 + q] = (ushort_t)lo;
        }
    }
    __syncthreads();

    int lrow = lane >> 3;
    int sg = (lane & 7) ^ lrow;
    auto issueB = [&](int kt, int buf) {
        int kb = k0 + kt * 64;
        for (int i = 0; i < 4; ++i) {          // 256 rows: wave covers 32 rows (4 x 8)
            int rbase = wid * 32 + i * 8;
            gload_lds16(Bm + (size_t)(rbase + lrow) * 65536 + kb + sg * 8, &Bs[buf][wid * 2048 + i * 512]);
        }
    };
    short8 ta[2], tb[2];
    float svr[2];
    auto gather = [&](int kt) {
        int kl = kt >> 1;
        for (int i = 0; i < 2; ++i) {
            int q = tid + i * 512;
            int row = q >> 3, slot = q & 7;
            int e0 = ((kt & 1) << 6) + slot * 8;
            int r = r_s[row * 8 + kl];
            svr[i] = sv_s[row * 8 + kl];
            ta[i] = *(const short8*)(Atab + r * 128 + e0);
            tb[i] = *(const short8*)(Btab + r * 128 + e0);
        }
    };
    auto cookwrite = [&](int buf) {
        for (int i = 0; i < 2; ++i) {
            int q = tid + i * 512;
            int row = q >> 3, slot = q & 7;
            float sv = svr[i];
            short8 o;
            for (int jj = 0; jj < 8; ++jj) {
                float y = fmaf(sv, bf2f((ushort_t)ta[i][jj]), bf2f((ushort_t)tb[i][jj]));
                y = y - fminf(fmaxf(y, -LAMBDA_), LAMBDA_);
                o[jj] = (short)f2bf_hw(y);
            }
            *(short8*)&As[buf][row * 64 + ((slot ^ (row & 7)) << 3)] = o;
        }
    };

    f32x4 acc[4][4] = {};
    issueB(0, 0);
    gather(0);
    cookwrite(0);
    __syncthreads();
    int cur = 0;
    for (int kt = 0; kt < 16; ++kt) {
        int nxt = cur ^ 1;
        if (kt + 1 < 16) { issueB(kt + 1, nxt); gather(kt + 1); }
        __builtin_amdgcn_s_setprio(1);
        for (int ks = 0; ks < 2; ++ks) {
            short8 a[4], b[4];
            int sl = ks * 4 + (lane >> 4);
            for (int mi = 0; mi < 4; ++mi) {
                int row = wr * 64 + mi * 16 + (lane & 15);
                a[mi] = *(const short8*)&As[cur][row * 64 + ((sl ^ (row & 7)) << 3)];
            }
            for (int ni = 0; ni < 4; ++ni) {
                int row = wc * 64 + ni * 16 + (lane & 15);
                b[ni] = *(const short8*)&Bs[cur][row * 64 + ((sl ^ (row & 7)) << 3)];
            }
            for (int mi = 0; mi < 4; ++mi)
                for (int ni = 0; ni < 4; ++ni)
                    acc[mi][ni] = __builtin_amdgcn_mfma_f32_16x16x32_bf16(a[mi], b[ni], acc[mi][ni], 0, 0, 0);
        }
        __builtin_amdgcn_s_setprio(0);
        if (kt + 1 < 16) cookwrite(nxt);
        __syncthreads();
        cur = nxt;
    }
    int mb0 = m0 + wr * 64 + ((lane >> 4) << 2);
    int nb0 = wc * 64 + (lane & 15);
    float* pbase = partial + (size_t)kc * 131072;
    for (int mi = 0; mi < 4; ++mi)
        for (int ni = 0; ni < 4; ++ni) {
            int mbase = mb0 + mi * 16;
            int n = nb0 + ni * 16;
            for (int r = 0; r < 4; ++r)
                pbase[(size_t)(mbase + r) * 256 + n] = acc[mi][ni][r];
        }
}

// ---------------- K10: final ----------------
__global__ __launch_bounds__(128) void k_final(const float* __restrict__ partial, const ushort_t* __restrict__ hl,
                                               const ushort_t* __restrict__ P2T, const float* __restrict__ p2v,
                                               const float* __restrict__ h2c, const float* __restrict__ fb1,
                                               const float* __restrict__ fw2, const float* __restrict__ fb2,
                                               float* __restrict__ out) {
    __shared__ float a_s[256];
    __shared__ float hl_s[256];
    int bn = blockIdx.x;
    int tid = threadIdx.x;
    {
        uint v = *(const uint*)(hl + (size_t)bn * 256 + tid * 2);
        hl_s[tid * 2] = bf2f((ushort_t)(v & 0xffff));
        hl_s[tid * 2 + 1] = bf2f((ushort_t)(v >> 16));
    }
    __syncthreads();
    for (int p = 0; p < 2; ++p) {
        int i = tid + p * 128;
        float acc = p2v[i] + h2c[(size_t)bn * 256 + i] + fb1[i];
#pragma unroll 8
        for (int kc = 0; kc < 64; ++kc)
            acc += partial[((size_t)kc * 512 + bn) * 256 + i];
        const ushort_t* prow = P2T + (size_t)i * 256;
#pragma unroll 4
        for (int jb = 0; jb < 32; ++jb) {
            short8 pv = *(const short8*)(prow + jb * 8);
            for (int j8 = 0; j8 < 8; ++j8)
                acc += hl_s[jb * 8 + j8] * bf2f((ushort_t)pv[j8]);
        }
        a_s[i] = leaky_(acc);
    }
    __syncthreads();
    if (tid < 96) {
        float acc = fb2[tid];
        for (int hh = 0; hh < 256; ++hh)
            acc += a_s[hh] * fw2[hh * 96 + tid];
        int b = bn >> 6, n = bn & 63;
        out[(size_t)(b * 96 + tid) * 64 + n] = acc;
    }
}

extern "C" void kernel_launch(void* const* d_in, const int* in_sizes, int n_in,
                              void* d_out, int out_size, void* d_ws, size_t ws_size,
                              hipStream_t stream) {
    const float* x   = (const float*)d_in[0];
    const float* emb = (const float*)d_in[1];
    const float* w1  = (const float*)d_in[2];
    const float* b1  = (const float*)d_in[3];
    const float* w2  = (const float*)d_in[4];
    const float* b2  = (const float*)d_in[5];
    const float* tw1 = (const float*)d_in[6];
    const float* tb1 = (const float*)d_in[7];
    const float* tw2 = (const float*)d_in[8];
    const float* tb2 = (const float*)d_in[9];
    const float* fw1 = (const float*)d_in[10];
    const float* fb1 = (const float*)d_in[11];
    const float* fw2 = (const float*)d_in[12];
    const float* fb2 = (const float*)d_in[13];
    float* out = (float*)d_out;

    char* W = (char*)d_ws;
    size_t off = 0;
    auto take = [&](size_t bytes) { size_t r = off; off += (bytes + 255) & ~(size_t)255; return r; };
    ushort_t* fw1T  = (ushort_t*)(W + take(33554432));        // [32768][512] bf16
    ushort_t* M2T   = (ushort_t*)(W + take(33554432));        // [256 h][65536 k'] bf16
    float* partial  = (float*)(W + take(64 * 512 * 256 * 4)); // [64 kc][512 bn][256 h] f32
    float* partialG = (float*)(W + take(8 * 512 * 1024 * 4)); // [8 kch][512 bn][1024 n] f32
    ushort_t* A1cat = (ushort_t*)(W + take(512 * 1536 * 2));
    ushort_t* B1cat = (ushort_t*)(W + take(1024 * 1536 * 2));
    ushort_t* Wt    = (ushort_t*)(W + take(512 * 512 * 2));
    ushort_t* tw2bf = (ushort_t*)(W + take(256 * 512 * 2));
    float* F1T      = (float*)(W + take(2 * 256 * 512 * 4)); // [2][h][t]
    ushort_t* F1sbf = (ushort_t*)(W + take(256 * 512 * 2));
    float* sbuf     = (float*)(W + take(512 * 512 * 4));
    ushort_t* hlbuf = (ushort_t*)(W + take(512 * 256 * 2));
    float* h2c      = (float*)(W + take(512 * 256 * 4));
    ushort_t* P2T   = (ushort_t*)(W + take(256 * 256 * 2));
    float* p2v      = (float*)(W + take(256 * 4));
    ushort_t* Atab  = (ushort_t*)(W + take(257 * 128 * 2));
    ushort_t* Btab  = (ushort_t*)(W + take(257 * 128 * 2));
    float* bpkey    = (float*)(W + take(256 * 4));
    float* u_g      = (float*)(W + take(256 * 4));
    int* idxs_g     = (int*)(W + take(256 * 4));
    (void)ws_size; (void)in_sizes; (void)n_in; (void)out_size;

    k_pre<<<3360, 256, 0, stream>>>(x, tw1, tw2, A1cat, B1cat, Wt, tw2bf);
    k_prep1<<<1, 256, 0, stream>>>(emb, w1, b1, u_g, idxs_g, bpkey);
    k_prep2<<<128, 256, 0, stream>>>(u_g, b1, w2, b2, idxs_g, Atab, Btab);
    k_transpose_fw1<<<4096, 256, 0, stream>>>(fw1, fw1T);
    k_reduce_F2<<<256, 256, 0, stream>>>(fw1T, emb, F1T);
    k_pack_F<<<256, 64, 0, stream>>>(F1T, F1T + 131072, tb2, B1cat, F1sbf, p2v);
    k_g1<<<256, 256, 0, stream>>>(A1cat, B1cat, partialG);
    k_reduceG1<<<2048, 256, 0, stream>>>(partialG, tb1, sbuf, hlbuf, h2c);
    k_gemm0<<<1024, 512, 0, stream>>>(Wt, fw1T, M2T);
    k_p2<<<4, 256, 0, stream>>>(tw2bf, F1sbf, P2T);
    // GEMM1 (fused softshrink-A, BN=256): partial[kc] = cook(s) @ M2T^T  (split-K 64)
    k_gemm1<<<256, 512, 0, stream>>>(sbuf, Atab, Btab, bpkey, M2T, partial);
    k_final<<<512, 128, 0, stream>>>(partial, hlbuf, P2T, p2v, h2c, fb1, fw2, fb2, out);
}

// Round 13
// 141.311 us; speedup vs baseline: 1.1696x; 1.1696x over previous
//
#include <hip/hip_runtime.h>
#include <hip/hip_bf16.h>

// B=8, T=512, N=64, E=128, H=256, P=96.  bn = b*64+n (512 rows).
// Identities:
//  xe = x_noD*emb  => rfft factorizes: spectral scalar s[bn,k] (packed: k<=256 real, k>256 imag)
//  mlp(s*emb) piecewise-linear in s (257 regions; tables Atab/Btab[r][e])
//  xt-part of flat@fw1:  h2[bn,h] = sum_{k,e} Yp[bn,k,e] * M2[k,e,h],
//      M2[k,(h,e)] = sum_t W[t,k] fw1[(t*128+e)*256+h]   (W = packed irfft basis)
//      Yp values are generated IN-REGISTER inside GEMM1 (fused softshrink), never materialized.
//  xn-part:   xn@F1s = hl@(tw2@F1s) + tb2@F1s,  F1s[t,h] = sum_e fw1
//  bias-part: x_noD@F1e,                        F1e[t,h] = sum_e (1+emb_e) fw1
//  s and x@F1e via hi/lo bf16 K-concat MFMA (A=[hi|lo|hi], B=[hi;hi;lo]) — G1 split-K.
// Round 13: dispatch fusion 12 -> 6 (launch-gap + tiny-kernel serial floor):
//  k_pre_plus = setup|pack_tw1|transpose_x|transpose_fw1|prep1 (all read only inputs)
//  k_mid      = reduceF (reduce_F2 with pack_F folded; F1T round-trip deleted) | prep2
//  k_g1p2     = g1 | p2
//  k_gemm0r   = gemm0 | reduceG1 (16MB reduce hidden under MFMA kernel)

typedef unsigned int uint;
typedef unsigned short ushort_t;
typedef __attribute__((ext_vector_type(4))) float f32x4;
typedef __attribute__((ext_vector_type(8))) short short8;

#define LAMBDA_ 0.001f
#define RSQRT512 0.044194173824159220f

__device__ __forceinline__ ushort_t f2bf(float f) {
    uint u = __float_as_uint(f);
    uint r = (u + 0x7FFFu + ((u >> 16) & 1u)) >> 16;
    return (ushort_t)r;
}
__device__ __forceinline__ ushort_t f2bf_hw(float f) {
    union { __hip_bfloat16 h; ushort_t u; } c;
    c.h = __float2bfloat16(f);
    return c.u;
}
__device__ __forceinline__ float bf2f(ushort_t v) { return __uint_as_float(((uint)v) << 16); }
__device__ __forceinline__ float leaky_(float v) { return v >= 0.f ? v : 0.01f * v; }

__device__ __forceinline__ void gload_lds16(const ushort_t* g, ushort_t* l) {
    __builtin_amdgcn_global_load_lds((const __attribute__((address_space(1))) void*)g,
                                     (__attribute__((address_space(3))) void*)l, 16, 0, 0);
}

// ---------------- D1: k_pre_plus: setup(3072) | pack_tw1(32) | transpose_x(256) |
//                      transpose_fw1(4096) | prep1(1); grid 7457 ----------------
__global__ __launch_bounds__(256) void k_pre_plus(const float* __restrict__ x, const float* __restrict__ tw1,
                                                  const float* __restrict__ tw2, const float* __restrict__ fw1,
                                                  const float* __restrict__ emb, const float* __restrict__ w1,
                                                  const float* __restrict__ b1,
                                                  ushort_t* __restrict__ A1cat, ushort_t* __restrict__ B1cat,
                                                  ushort_t* __restrict__ Wt, ushort_t* __restrict__ tw2_bf,
                                                  ushort_t* __restrict__ fw1T,
                                                  float* __restrict__ u_g, int* __restrict__ idxs_g,
                                                  float* __restrict__ bpkey_g) {
    __shared__ float tile[64 * 65];
    __shared__ float key_s[256];
    __shared__ int idx_s[256];
    int bid = blockIdx.x;
    int tid = threadIdx.x;
    if (bid < 3072) {
        int region = bid >> 10;
        int id = ((bid & 1023) << 8) + tid;
        int a = id >> 9, c = id & 511;
        if (region == 0) {       // B1cat rows 0-511: D[t=c][k=a], hi|hi|lo
            int f = (a <= 256) ? a : (a - 256);
            int m = (c * f) & 511;
            float ang = (float)m * (6.283185307179586f / 512.0f);
            float v = ((a <= 256) ? cosf(ang) : -sinf(ang)) * RSQRT512;
            ushort_t hi = f2bf(v);
            ushort_t lo = f2bf(v - bf2f(hi));
            size_t row = (size_t)a * 1536;
            B1cat[row + c] = hi;
            B1cat[row + 512 + c] = hi;
            B1cat[row + 1024 + c] = lo;
        } else if (region == 1) {  // Wt[k=a][t=c]
            int f = (a <= 256) ? a : (a - 256);
            int m = (c * f) & 511;
            float ang = (float)m * (6.283185307179586f / 512.0f);
            float v = ((a <= 256) ? cosf(ang) : -sinf(ang)) * RSQRT512;
            float sc = (a == 0 || a == 256) ? 1.0f : 2.0f;
            Wt[id] = f2bf(v * sc);
        } else {                   // tw2_bf (512 blocks used)
            if ((bid & 1023) < 512) tw2_bf[id] = f2bf(tw2[id]);
        }
    } else if (bid < 3104) {
        // pack_tw1 -> B1cat rows 512-767 (transposed, hi|hi|lo)
        int b = bid - 3072;
        int t0 = (b & 7) << 6, h0 = (b >> 3) << 6;
        float (*t64)[65] = (float(*)[65])tile;
        for (int i = 0; i < 16; ++i) {
            int idx = tid + i * 256;
            int r = idx >> 6, cc = idx & 63;
            t64[r][cc] = tw1[(size_t)(t0 + r) * 256 + h0 + cc];
        }
        __syncthreads();
        for (int i = 0; i < 16; ++i) {
            int idx = tid + i * 256;
            int rr = idx >> 6, cc2 = idx & 63;
            float v = t64[cc2][rr];
            ushort_t hi = f2bf(v);
            ushort_t lo = f2bf(v - bf2f(hi));
            size_t row = (size_t)(512 + h0 + rr) * 1536;
            int t = t0 + cc2;
            B1cat[row + t] = hi;
            B1cat[row + 512 + t] = hi;
            B1cat[row + 1024 + t] = lo;
        }
    } else if (bid < 3360) {
        // transpose_x [8][512][64] -> A1cat [512 bn][1536] (hi|lo|hi)
        int b = bid - 3104;
        int bb = b >> 5;
        int rem = b & 31;
        int t0 = (rem >> 1) << 5;
        int n0 = (rem & 1) << 5;
        int tx = tid & 31, ty = tid >> 5;
        float (*t32)[33] = (float(*)[33])tile;
        for (int i = 0; i < 4; ++i) {
            int tt = ty * 4 + i;
            t32[tt][tx] = x[(size_t)(bb * 512 + t0 + tt) * 64 + n0 + tx];
        }
        __syncthreads();
        for (int i = 0; i < 4; ++i) {
            int nn = ty * 4 + i;
            float v = t32[tx][nn];
            ushort_t hi = f2bf(v);
            ushort_t lo = f2bf(v - bf2f(hi));
            size_t row = (size_t)(bb * 64 + n0 + nn) * 1536;
            int t = t0 + tx;
            A1cat[row + t] = hi;
            A1cat[row + 512 + t] = lo;
            A1cat[row + 1024 + t] = hi;
        }
    } else if (bid < 7456) {
        // transpose_fw1: fw1 [(t,e)][h] f32 -> fw1T[(h*128+e)][t] bf16
        int b = bid - 3360;
        int e  = b & 127;
        int hb = (b >> 7) & 3;
        int tt = b >> 9;
        int t0 = tt << 6, h0 = hb << 6;
        float (*t64)[65] = (float(*)[65])tile;
        for (int i = 0; i < 4; ++i) {
            int idx = tid + i * 256;
            int r = idx >> 4, c4 = idx & 15;
            const float* src = fw1 + ((size_t)(t0 + r) * 128 + e) * 256 + h0 + c4 * 4;
            float4 v = *(const float4*)src;
            t64[r][c4 * 4 + 0] = v.x;
            t64[r][c4 * 4 + 1] = v.y;
            t64[r][c4 * 4 + 2] = v.z;
            t64[r][c4 * 4 + 3] = v.w;
        }
        __syncthreads();
        for (int p = 0; p < 2; ++p) {
            int idx = tid + p * 256;
            int hh = idx >> 3, tg = idx & 7;
            short8 o;
            for (int j = 0; j < 8; ++j) o[j] = (short)f2bf(t64[tg * 8 + j][hh]);
            *(short8*)(fw1T + ((size_t)(h0 + hh) * 128 + e) * 512 + t0 + tg * 8) = o;
        }
    } else {
        // prep1: u = emb@w1, breakpoint keys, bitonic sort
        float acc = 0.f;
#pragma unroll 8
        for (int e = 0; e < 128; ++e) acc += emb[e] * w1[e * 256 + tid];
        u_g[tid] = acc;
        float bb0 = b1[tid];
        key_s[tid] = (acc == 0.f) ? INFINITY : (-bb0 / acc);
        idx_s[tid] = tid;
        __syncthreads();
        for (int k = 2; k <= 256; k <<= 1) {
            for (int j = k >> 1; j > 0; j >>= 1) {
                int ixj = tid ^ j;
                if (ixj > tid) {
                    bool up = ((tid & k) == 0);
                    float a0 = key_s[tid], a1 = key_s[ixj];
                    if ((a0 > a1) == up) {
                        key_s[tid] = a1; key_s[ixj] = a0;
                        int t0 = idx_s[tid]; idx_s[tid] = idx_s[ixj]; idx_s[ixj] = t0;
                    }
                }
                __syncthreads();
            }
        }
        bpkey_g[tid] = key_s[tid];
        idxs_g[tid] = idx_s[tid];
    }
}

// ---------------- D2: k_mid: reduceF(256: reduce_F2+pack_F fused) | prep2(128); grid 384 ----------------
__global__ __launch_bounds__(256) void k_mid(const ushort_t* __restrict__ fw1T, const float* __restrict__ emb,
                                             const float* __restrict__ tb2,
                                             ushort_t* __restrict__ B1cat, ushort_t* __restrict__ F1sbf,
                                             float* __restrict__ p2v,
                                             const float* __restrict__ u_g, const float* __restrict__ b1,
                                             const float* __restrict__ w2, const float* __restrict__ b2,
                                             const int* __restrict__ idxs_g,
                                             ushort_t* __restrict__ Atab, ushort_t* __restrict__ Btab) {
    __shared__ float embs[128];
    __shared__ float red[256];
    __shared__ float sA[256], sB[256];
    int bid = blockIdx.x;
    int tid = threadIdx.x;
    if (bid < 256) {
        // reduceF: h = bid. F1s/F1e sums over e from fw1T, then pack directly.
        int h = bid;
        if (tid < 128) embs[tid] = 1.f + emb[tid];
        __syncthreads();
        int t2 = tid * 2;
        const ushort_t* base = fw1T + ((size_t)h << 16) + t2;
        float as0 = 0.f, as1 = 0.f, ae0 = 0.f, ae1 = 0.f;
#pragma unroll 4
        for (int e = 0; e < 128; ++e) {
            uint v = *(const uint*)(base + (size_t)e * 512);
            float v0 = bf2f((ushort_t)(v & 0xffff));
            float v1 = bf2f((ushort_t)(v >> 16));
            float w = embs[e];
            as0 += v0; as1 += v1;
            ae0 += w * v0; ae1 += w * v1;
        }
        // pack: F1sbf row h (bf16), B1cat row 768+h (F1e hi|hi|lo), p2v[h] = sum tb2*F1s
        *(uint*)(F1sbf + (size_t)h * 512 + t2) = (uint)f2bf(as0) | ((uint)f2bf(as1) << 16);
        ushort_t hi0 = f2bf(ae0), hi1 = f2bf(ae1);
        ushort_t lo0 = f2bf(ae0 - bf2f(hi0)), lo1 = f2bf(ae1 - bf2f(hi1));
        size_t row = (size_t)(768 + h) * 1536;
        uint hpk = (uint)hi0 | ((uint)hi1 << 16);
        *(uint*)(B1cat + row + t2) = hpk;
        *(uint*)(B1cat + row + 512 + t2) = hpk;
        *(uint*)(B1cat + row + 1024 + t2) = (uint)lo0 | ((uint)lo1 << 16);
        red[tid] = tb2[t2] * as0 + tb2[t2 + 1] * as1;
        __syncthreads();
        for (int off = 128; off > 0; off >>= 1) {
            if (tid < off) red[tid] += red[tid + off];
            __syncthreads();
        }
        if (tid == 0) p2v[h] = red[0];
    } else {
        // prep2: per-e prefix-scan table build; e = bid - 256
        int e = bid - 256, r = tid;
        float uu0 = u_g[r], bb0 = b1[r];
        float w0 = w2[r * 128 + e];
        float c = (uu0 < 0.f || (uu0 == 0.f && bb0 >= 0.f)) ? 1.0f : 0.01f;
        float bA = c * uu0 * w0, bB = c * bb0 * w0;
        int h = idxs_g[r];
        float uu = u_g[h], bb = b1[h];
        float w = w2[h * 128 + e];
        float sgn = (uu > 0.f) ? 0.99f : -0.99f;
        float dA = sgn * uu * w, dB = sgn * bb * w;
        sA[r] = bA; sB[r] = bB;
        __syncthreads();
        for (int off = 128; off > 0; off >>= 1) {
            if (r < off) { sA[r] += sA[r + off]; sB[r] += sB[r + off]; }
            __syncthreads();
        }
        float baseA = sA[0], baseB = sB[0] + b2[e];
        __syncthreads();
        sA[r] = dA; sB[r] = dB;
        __syncthreads();
        for (int off = 1; off < 256; off <<= 1) {
            float vA = (r >= off) ? sA[r - off] : 0.f;
            float vB = (r >= off) ? sB[r - off] : 0.f;
            __syncthreads();
            sA[r] += vA; sB[r] += vB;
            __syncthreads();
        }
        if (r == 0) { Atab[e] = f2bf(baseA); Btab[e] = f2bf(baseB); }
        Atab[(r + 1) * 128 + e] = f2bf(baseA + sA[r]);
        Btab[(r + 1) * 128 + e] = f2bf(baseB + sB[r]);
    }
}

// ---------------- D3: k_g1p2: g1(256) | p2(4); grid 260 ----------------
__global__ __launch_bounds__(256) void k_g1p2(const ushort_t* __restrict__ A, const ushort_t* __restrict__ Bm,
                                              float* __restrict__ partialG,
                                              const ushort_t* __restrict__ tw2bf, const ushort_t* __restrict__ F1sbf,
                                              ushort_t* __restrict__ P2T) {
    __shared__ ushort_t As[128 * 72];
    __shared__ ushort_t Bs[128 * 72];
    int tid = threadIdx.x;
    int lane = tid & 63, wid = tid >> 6;
    int wr = wid >> 1, wc = wid & 1;
    int bid = blockIdx.x;
    f32x4 acc[4][4] = {};
    if (bid < 256) {
        // g1: split-K G1 partials. M=512, N=1024, K chunk of 192 (3 kt of 64).
        int kch = bid & 7, tilei = bid >> 3;
        int nt = tilei & 7, mt = tilei >> 3;
        int m0 = mt * 128, n0 = nt * 128;
        for (int kt = 0; kt < 3; ++kt) {
            int kb = kch * 192 + kt * 64;
            __syncthreads();
            {
                uint4 va[4], vb[4];
                for (int i = 0; i < 4; ++i) {
                    int q = tid + i * 256;
                    int row = q >> 3, kcc = (q & 7) << 3;
                    va[i] = *(const uint4*)(A + (size_t)(m0 + row) * 1536 + kb + kcc);
                    vb[i] = *(const uint4*)(Bm + (size_t)(n0 + row) * 1536 + kb + kcc);
                }
                for (int i = 0; i < 4; ++i) {
                    int q = tid + i * 256;
                    int row = q >> 3, kcc = (q & 7) << 3;
                    *(uint4*)&As[row * 72 + kcc] = va[i];
                    *(uint4*)&Bs[row * 72 + kcc] = vb[i];
                }
            }
            __syncthreads();
            for (int ks = 0; ks < 2; ++ks) {
                short8 a[4], b[4];
                int kk = ks * 32 + (lane >> 4) * 8;
                for (int mi = 0; mi < 4; ++mi)
                    a[mi] = *(const short8*)&As[(wr * 64 + mi * 16 + (lane & 15)) * 72 + kk];
                for (int ni = 0; ni < 4; ++ni)
                    b[ni] = *(const short8*)&Bs[(wc * 64 + ni * 16 + (lane & 15)) * 72 + kk];
                for (int mi = 0; mi < 4; ++mi)
                    for (int ni = 0; ni < 4; ++ni)
                        acc[mi][ni] = __builtin_amdgcn_mfma_f32_16x16x32_bf16(a[mi], b[ni], acc[mi][ni], 0, 0, 0);
            }
        }
        float* pbase = partialG + (size_t)kch * 524288;
        int mb0 = m0 + wr * 64 + ((lane >> 4) << 2);
        int nb0 = n0 + wc * 64 + (lane & 15);
        for (int mi = 0; mi < 4; ++mi)
            for (int ni = 0; ni < 4; ++ni) {
                int mbase = mb0 + mi * 16;
                int n = nb0 + ni * 16;
                for (int r = 0; r < 4; ++r)
                    pbase[(size_t)(mbase + r) * 1024 + n] = acc[mi][ni][r];
            }
    } else {
        // p2: P2T = (tw2 @ F1s^T)^T; M=N=256, K=512
        int b2i = bid - 256;
        int nt = b2i & 1, mt = b2i >> 1;
        int m0 = mt * 128, n0 = nt * 128;
        for (int kt = 0; kt < 8; ++kt) {
            int kb = kt * 64;
            __syncthreads();
            {
                uint4 va[4], vb[4];
                for (int i = 0; i < 4; ++i) {
                    int q = tid + i * 256;
                    int row = q >> 3, kcc = (q & 7) << 3;
                    va[i] = *(const uint4*)(tw2bf + (size_t)(m0 + row) * 512 + kb + kcc);
                    vb[i] = *(const uint4*)(F1sbf + (size_t)(n0 + row) * 512 + kb + kcc);
                }
                for (int i = 0; i < 4; ++i) {
                    int q = tid + i * 256;
                    int row = q >> 3, kcc = (q & 7) << 3;
                    *(uint4*)&As[row * 72 + kcc] = va[i];
                    *(uint4*)&Bs[row * 72 + kcc] = vb[i];
                }
            }
            __syncthreads();
            for (int ks = 0; ks < 2; ++ks) {
                short8 a[4], b[4];
                int kk = ks * 32 + (lane >> 4) * 8;
                for (int mi = 0; mi < 4; ++mi)
                    a[mi] = *(const short8*)&As[(wr * 64 + mi * 16 + (lane & 15)) * 72 + kk];
                for (int ni = 0; ni < 4; ++ni)
                    b[ni] = *(const short8*)&Bs[(wc * 64 + ni * 16 + (lane & 15)) * 72 + kk];
                for (int mi = 0; mi < 4; ++mi)
                    for (int ni = 0; ni < 4; ++ni)
                        acc[mi][ni] = __builtin_amdgcn_mfma_f32_16x16x32_bf16(a[mi], b[ni], acc[mi][ni], 0, 0, 0);
            }
        }
        int mb0 = m0 + wr * 64 + ((lane >> 4) << 2);
        int nb0 = n0 + wc * 64 + (lane & 15);
        for (int mi = 0; mi < 4; ++mi)
            for (int ni = 0; ni < 4; ++ni) {
                int mbase = mb0 + mi * 16;
                int n = nb0 + ni * 16;
                ushort4 o;
                o.x = f2bf(acc[mi][ni][0]);
                o.y = f2bf(acc[mi][ni][1]);
                o.z = f2bf(acc[mi][ni][2]);
                o.w = f2bf(acc[mi][ni][3]);
                *(ushort4*)(P2T + (size_t)n * 256 + mbase) = o;
            }
    }
}

// ---------------- D4: k_gemm0r: gemm0(1024) | reduceG1(1024); grid 2048, 512 thr ----------------
__global__ __launch_bounds__(512) void k_gemm0r(const ushort_t* __restrict__ A, const ushort_t* __restrict__ Bm,
                                                ushort_t* __restrict__ M2T,
                                                const float* __restrict__ partialG, const float* __restrict__ tb1,
                                                float* __restrict__ s, ushort_t* __restrict__ hl,
                                                float* __restrict__ h2c) {
    __shared__ ushort_t As[2][128 * 64];
    __shared__ ushort_t Bs[2][128 * 64];
    int tid = threadIdx.x;
    int bid = blockIdx.x;
    if (bid >= 1024) {
        // reduceG1: sum 8 partials, route epilogue to s / hl / h2c
        int id = (bid - 1024) * 512 + tid;    // 1024 blocks x 512 = 524288
        int m = id >> 10, n = id & 1023;
        float acc = 0.f;
#pragma unroll
        for (int kc = 0; kc < 8; ++kc)
            acc += partialG[(size_t)kc * 524288 + id];
        if (n < 512) s[(size_t)m * 512 + n] = acc;
        else if (n < 768) hl[(size_t)m * 256 + (n - 512)] = f2bf(leaky_(acc + tb1[n - 512]));
        else h2c[(size_t)m * 256 + (n - 768)] = acc;
        return;
    }
    int lane = tid & 63, wid = tid >> 6;
    int wr = wid >> 2, wc = wid & 3;          // 2 x 4 waves; wave tile 64m x 32n
    int xx = bid & 7, y = bid >> 3;
    int mt = y & 3;
    int nt = ((y >> 2) << 3) | xx;
    int m0 = mt * 128, n0 = nt * 128;
    int lrow = lane >> 3;
    int sg = (lane & 7) ^ lrow;               // swizzled source 16B-slot
    auto issue = [&](int kt, int buf) {
        int kb = kt * 64;
        for (int i = 0; i < 2; ++i) {
            int rbase = wid * 16 + i * 8;
            gload_lds16(A + (size_t)(m0 + rbase + lrow) * 512 + kb + sg * 8, &As[buf][wid * 1024 + i * 512]);
            gload_lds16(Bm + (size_t)(n0 + rbase + lrow) * 512 + kb + sg * 8, &Bs[buf][wid * 1024 + i * 512]);
        }
    };
    f32x4 acc[4][2] = {};
    issue(0, 0);
    __syncthreads();
    int cur = 0;
    for (int kt = 0; kt < 8; ++kt) {
        int nxt = cur ^ 1;
        if (kt + 1 < 8) issue(kt + 1, nxt);
        __builtin_amdgcn_s_setprio(1);
        for (int ks = 0; ks < 2; ++ks) {
            short8 a[4], b[2];
            int sl = ks * 4 + (lane >> 4);
            for (int mi = 0; mi < 4; ++mi) {
                int row = wr * 64 + mi * 16 + (lane & 15);
                a[mi] = *(const short8*)&As[cur][row * 64 + ((sl ^ (row & 7)) << 3)];
            }
            for (int ni = 0; ni < 2; ++ni) {
                int row = wc * 32 + ni * 16 + (lane & 15);
                b[ni] = *(const short8*)&Bs[cur][row * 64 + ((sl ^ (row & 7)) << 3)];
            }
            for (int mi = 0; mi < 4; ++mi)
                for (int ni = 0; ni < 2; ++ni)
                    acc[mi][ni] = __builtin_amdgcn_mfma_f32_16x16x32_bf16(a[mi], b[ni], acc[mi][ni], 0, 0, 0);
        }
        __builtin_amdgcn_s_setprio(0);
        __syncthreads();
        cur = nxt;
    }
    ushort_t* cstage = &As[0][0];
    for (int mi = 0; mi < 4; ++mi) {
        int ml = wr * 64 + mi * 16 + ((lane >> 4) << 2);
        for (int ni = 0; ni < 2; ++ni) {
            int nl = wc * 32 + ni * 16 + (lane & 15);
            for (int r = 0; r < 4; ++r) {
                int row = ml + r;
                cstage[row * 128 + (nl ^ ((row & 7) << 4))] = f2bf(acc[mi][ni][r]);
            }
        }
    }
    __syncthreads();
    short8* d8 = (short8*)(M2T + ((size_t)(n0 >> 7) << 16) + (size_t)m0 * 128);
    for (int i = 0; i < 4; ++i) {
        int p = tid + i * 512;
        int row = p >> 4;
        int col0 = (p & 15) * 8;
        d8[p] = *(const short8*)&cstage[row * 128 + (col0 ^ ((row & 7) << 4))];
    }
}

// ---------------- D5: GEMM1 (fused): partial[kc] = cook(s) @ M2T^T chunk ----------------
// M=512, N=256 (full), K=65536. BM=128, BN=256, split-K 64 chunks of 1024.
// grid 256 = xcd(8) x [kcl(8) x mt(4)]; 8 waves 2x4 (wave tile 64x64).
__global__ __launch_bounds__(512) void k_gemm1(const float* __restrict__ s,
                                               const ushort_t* __restrict__ Atab, const ushort_t* __restrict__ Btab,
                                               const float* __restrict__ bpkey,
                                               const ushort_t* __restrict__ Bm,
                                               float* __restrict__ partial) {
    __shared__ ushort_t As[2][128 * 64];     // 32 KB
    __shared__ ushort_t Bs[2][256 * 64];     // 64 KB
    __shared__ float sv_s[1024];
    __shared__ ushort_t r_s[1024];
    __shared__ float bp_s[256];
    int tid = threadIdx.x;
    int lane = tid & 63, wid = tid >> 6;
    int wr = wid >> 2, wc = wid & 3;           // wave tile 64m x 64n
    int bid = blockIdx.x;
    int xcd = bid & 7, j = bid >> 3;
    int kcl = j & 7, mt = j >> 3;
    int kc = xcd * 8 + kcl;
    int m0 = mt * 128;
    int k0 = kc * 1024;
    if (tid < 256) bp_s[tid] = bpkey[tid];
    __syncthreads();
    {
        int row = tid >> 2, j2 = (tid & 3) * 2;
        float2 sv2 = *(const float2*)(s + (size_t)(m0 + row) * 512 + kc * 8 + j2);
        float svv[2] = {sv2.x, sv2.y};
        for (int q = 0; q < 2; ++q) {
            float sv = svv[q];
            int lo = 0, hi = 256;
            while (lo < hi) { int mid = (lo + hi) >> 1; if (bp_s[mid] <= sv) lo = mid + 1; else hi = mid; }
            sv_s[row * 8 + j2 + q] = sv;
            r_s[row * 8 + j2 + q] = (ushort_t)lo;
        }
    }
    __syncthreads();

    int lrow = lane >> 3;
    int sg = (lane & 7) ^ lrow;
    auto issueB = [&](int kt, int buf) {
        int kb = k0 + kt * 64;
        for (int i = 0; i < 4; ++i) {
            int rbase = wid * 32 + i * 8;
            gload_lds16(Bm + (size_t)(rbase + lrow) * 65536 + kb + sg * 8, &Bs[buf][wid * 2048 + i * 512]);
        }
    };
    short8 ta[2], tb[2];
    float svr[2];
    auto gather = [&](int kt) {
        int kl = kt >> 1;
        for (int i = 0; i < 2; ++i) {
            int q = tid + i * 512;
            int row = q >> 3, slot = q & 7;
            int e0 = ((kt & 1) << 6) + slot * 8;
            int r = r_s[row * 8 + kl];
            svr[i] = sv_s[row * 8 + kl];
            ta[i] = *(const short8*)(Atab + r * 128 + e0);
            tb[i] = *(const short8*)(Btab + r * 128 + e0);
        }
    };
    auto cookwrite = [&](int buf) {
        for (int i = 0; i < 2; ++i) {
            int q = tid + i * 512;
            int row = q >> 3, slot = q & 7;
            float sv = svr[i];
            short8 o;
            for (int jj = 0; jj < 8; ++jj) {
                float y = fmaf(sv, bf2f((ushort_t)ta[i][jj]), bf2f((ushort_t)tb[i][jj]));
                y = y - fminf(fmaxf(y, -LAMBDA_), LAMBDA_);
                o[jj] = (short)f2bf_hw(y);
            }
            *(short8*)&As[buf][row * 64 + ((slot ^ (row & 7)) << 3)] = o;
        }
    };

    f32x4 acc[4][4] = {};
    issueB(0, 0);
    gather(0);
    cookwrite(0);
    __syncthreads();
    int cur = 0;
    for (int kt = 0; kt < 16; ++kt) {
        int nxt = cur ^ 1;
        if (kt + 1 < 16) { issueB(kt + 1, nxt); gather(kt + 1); }
        __builtin_amdgcn_s_setprio(1);
        for (int ks = 0; ks < 2; ++ks) {
            short8 a[4], b[4];
            int sl = ks * 4 + (lane >> 4);
            for (int mi = 0; mi < 4; ++mi) {
                int row = wr * 64 + mi * 16 + (lane & 15);
                a[mi] = *(const short8*)&As[cur][row * 64 + ((sl ^ (row & 7)) << 3)];
            }
            for (int ni = 0; ni < 4; ++ni) {
                int row = wc * 64 + ni * 16 + (lane & 15);
                b[ni] = *(const short8*)&Bs[cur][row * 64 + ((sl ^ (row & 7)) << 3)];
            }
            for (int mi = 0; mi < 4; ++mi)
                for (int ni = 0; ni < 4; ++ni)
                    acc[mi][ni] = __builtin_amdgcn_mfma_f32_16x16x32_bf16(a[mi], b[ni], acc[mi][ni], 0, 0, 0);
        }
        __builtin_amdgcn_s_setprio(0);
        if (kt + 1 < 16) cookwrite(nxt);
        __syncthreads();
        cur = nxt;
    }
    int mb0 = m0 + wr * 64 + ((lane >> 4) << 2);
    int nb0 = wc * 64 + (lane & 15);
    float* pbase = partial + (size_t)kc * 131072;
    for (int mi = 0; mi < 4; ++mi)
        for (int ni = 0; ni < 4; ++ni) {
            int mbase = mb0 + mi * 16;
            int n = nb0 + ni * 16;
            for (int r = 0; r < 4; ++r)
                pbase[(size_t)(mbase + r) * 256 + n] = acc[mi][ni][r];
        }
}

// ---------------- D6: k_final ----------------
__global__ __launch_bounds__(128) void k_final(const float* __restrict__ partial, const ushort_t* __restrict__ hl,
                                               const ushort_t* __restrict__ P2T, const float* __restrict__ p2v,
                                               const float* __restrict__ h2c, const float* __restrict__ fb1,
                                               const float* __restrict__ fw2, const float* __restrict__ fb2,
                                               float* __restrict__ out) {
    __shared__ float a_s[256];
    __shared__ float hl_s[256];
    int bn = blockIdx.x;
    int tid = threadIdx.x;
    {
        uint v = *(const uint*)(hl + (size_t)bn * 256 + tid * 2);
        hl_s[tid * 2] = bf2f((ushort_t)(v & 0xffff));
        hl_s[tid * 2 + 1] = bf2f((ushort_t)(v >> 16));
    }
    __syncthreads();
    for (int p = 0; p < 2; ++p) {
        int i = tid + p * 128;
        float acc = p2v[i] + h2c[(size_t)bn * 256 + i] + fb1[i];
#pragma unroll 8
        for (int kc = 0; kc < 64; ++kc)
            acc += partial[((size_t)kc * 512 + bn) * 256 + i];
        const ushort_t* prow = P2T + (size_t)i * 256;
#pragma unroll 4
        for (int jb = 0; jb < 32; ++jb) {
            short8 pv = *(const short8*)(prow + jb * 8);
            for (int j8 = 0; j8 < 8; ++j8)
                acc += hl_s[jb * 8 + j8] * bf2f((ushort_t)pv[j8]);
        }
        a_s[i] = leaky_(acc);
    }
    __syncthreads();
    if (tid < 96) {
        float acc = fb2[tid];
        for (int hh = 0; hh < 256; ++hh)
            acc += a_s[hh] * fw2[hh * 96 + tid];
        int b = bn >> 6, n = bn & 63;
        out[(size_t)(b * 96 + tid) * 64 + n] = acc;
    }
}

extern "C" void kernel_launch(void* const* d_in, const int* in_sizes, int n_in,
                              void* d_out, int out_size, void* d_ws, size_t ws_size,
                              hipStream_t stream) {
    const float* x   = (const float*)d_in[0];
    const float* emb = (const float*)d_in[1];
    const float* w1  = (const float*)d_in[2];
    const float* b1  = (const float*)d_in[3];
    const float* w2  = (const float*)d_in[4];
    const float* b2  = (const float*)d_in[5];
    const float* tw1 = (const float*)d_in[6];
    const float* tb1 = (const float*)d_in[7];
    const float* tw2 = (const float*)d_in[8];
    const float* tb2 = (const float*)d_in[9];
    const float* fw1 = (const float*)d_in[10];
    const float* fb1 = (const float*)d_in[11];
    const float* fw2 = (const float*)d_in[12];
    const float* fb2 = (const float*)d_in[13];
    float* out = (float*)d_out;

    char* W = (char*)d_ws;
    size_t off = 0;
    auto take = [&](size_t bytes) { size_t r = off; off += (bytes + 255) & ~(size_t)255; return r; };
    ushort_t* fw1T  = (ushort_t*)(W + take(33554432));        // [32768][512] bf16
    ushort_t* M2T   = (ushort_t*)(W + take(33554432));        // [256 h][65536 k'] bf16
    float* partial  = (float*)(W + take(64 * 512 * 256 * 4)); // [64 kc][512 bn][256 h] f32
    float* partialG = (float*)(W + take(8 * 512 * 1024 * 4)); // [8 kch][512 bn][1024 n] f32
    ushort_t* A1cat = (ushort_t*)(W + take(512 * 1536 * 2));
    ushort_t* B1cat = (ushort_t*)(W + take(1024 * 1536 * 2));
    ushort_t* Wt    = (ushort_t*)(W + take(512 * 512 * 2));
    ushort_t* tw2bf = (ushort_t*)(W + take(256 * 512 * 2));
    ushort_t* F1sbf = (ushort_t*)(W + take(256 * 512 * 2));
    float* sbuf     = (float*)(W + take(512 * 512 * 4));
    ushort_t* hlbuf = (ushort_t*)(W + take(512 * 256 * 2));
    float* h2c      = (float*)(W + take(512 * 256 * 4));
    ushort_t* P2T   = (ushort_t*)(W + take(256 * 256 * 2));
    float* p2v      = (float*)(W + take(256 * 4));
    ushort_t* Atab  = (ushort_t*)(W + take(257 * 128 * 2));
    ushort_t* Btab  = (ushort_t*)(W + take(257 * 128 * 2));
    float* bpkey    = (float*)(W + take(256 * 4));
    float* u_g      = (float*)(W + take(256 * 4));
    int* idxs_g     = (int*)(W + take(256 * 4));
    (void)ws_size; (void)in_sizes; (void)n_in; (void)out_size;

    // D1: setup | pack_tw1 | transpose_x | transpose_fw1 | prep1
    k_pre_plus<<<7457, 256, 0, stream>>>(x, tw1, tw2, fw1, emb, w1, b1,
                                         A1cat, B1cat, Wt, tw2bf, fw1T, u_g, idxs_g, bpkey);
    // D2: reduceF (reduce_F2 + pack_F fused) | prep2
    k_mid<<<384, 256, 0, stream>>>(fw1T, emb, tb2, B1cat, F1sbf, p2v,
                                   u_g, b1, w2, b2, idxs_g, Atab, Btab);
    // D3: g1 split-K | p2
    k_g1p2<<<260, 256, 0, stream>>>(A1cat, B1cat, partialG, tw2bf, F1sbf, P2T);
    // D4: gemm0 | reduceG1
    k_gemm0r<<<2048, 512, 0, stream>>>(Wt, fw1T, M2T, partialG, tb1, sbuf, hlbuf, h2c);
    // D5: GEMM1 (fused softshrink-A, BN=256, split-K 64)
    k_gemm1<<<256, 512, 0, stream>>>(sbuf, Atab, Btab, bpkey, M2T, partial);
    // D6: final
    k_final<<<512, 128, 0, stream>>>(partial, hlbuf, P2T, p2v, h2c, fb1, fw2, fb2, out);
}

// Round 14
// 137.406 us; speedup vs baseline: 1.2029x; 1.0284x over previous
//
#include <hip/hip_runtime.h>
#include <hip/hip_bf16.h>

// B=8, T=512, N=64, E=128, H=256, P=96.  bn = b*64+n (512 rows).
// Identities:
//  xe = x_noD*emb  => rfft factorizes: spectral scalar s[bn,k] (packed: k<=256 real, k>256 imag)
//  mlp(s*emb) piecewise-linear in s (257 regions; tables Atab/Btab[r][e])
//  xt-part of flat@fw1:  h2[bn,h] = sum_{k,e} Yp[bn,k,e] * M2[k,e,h],
//      M2[k,(h,e)] = sum_t W[t,k] fw1[(t*128+e)*256+h]   (W = packed irfft basis)
//      Yp values are generated IN-REGISTER inside GEMM1 (fused softshrink), never materialized.
//  xn-part:   xn@F1s = hl@(tw2@F1s) + tb2@F1s,  F1s[t,h] = sum_e fw1
//  bias-part: x_noD@F1e,                        F1e[t,h] = sum_e (1+emb_e) fw1
//  s and x@F1e via hi/lo bf16 K-concat MFMA (A=[hi|lo|hi], B=[hi;hi;lo]) — G1 split-K.
// Round 14: 6 -> 5 dispatches. k_big3 = gemm0|g1|p2 (g1/p2 on gemm0's 512-thr gload+swizzle
//  loop; their ~10us hides under gemm0). reduceG1 deleted: gemm1 sums its s-slice from
//  partialG (same order => bit-identical); final computes hl/h2c inline (hl stays f32).

typedef unsigned int uint;
typedef unsigned short ushort_t;
typedef __attribute__((ext_vector_type(4))) float f32x4;
typedef __attribute__((ext_vector_type(8))) short short8;

#define LAMBDA_ 0.001f
#define RSQRT512 0.044194173824159220f

__device__ __forceinline__ ushort_t f2bf(float f) {
    uint u = __float_as_uint(f);
    uint r = (u + 0x7FFFu + ((u >> 16) & 1u)) >> 16;
    return (ushort_t)r;
}
__device__ __forceinline__ ushort_t f2bf_hw(float f) {
    union { __hip_bfloat16 h; ushort_t u; } c;
    c.h = __float2bfloat16(f);
    return c.u;
}
__device__ __forceinline__ float bf2f(ushort_t v) { return __uint_as_float(((uint)v) << 16); }
__device__ __forceinline__ float leaky_(float v) { return v >= 0.f ? v : 0.01f * v; }

__device__ __forceinline__ void gload_lds16(const ushort_t* g, ushort_t* l) {
    __builtin_amdgcn_global_load_lds((const __attribute__((address_space(1))) void*)g,
                                     (__attribute__((address_space(3))) void*)l, 16, 0, 0);
}

// Shared 512-thread 128x128-tile dbuf loop (gload_lds + source-pre-swizzle, 1 barrier/K-step).
// Wave layout: 8 waves 2m x 4n; wave tile 64m x 32n; acc[4][2].
__device__ __forceinline__ void tile_loop512(const ushort_t* __restrict__ A, int lda,
                                             const ushort_t* __restrict__ Bm, int ldb,
                                             int m0, int n0, int k0, int kIters,
                                             f32x4 (&acc)[4][2],
                                             ushort_t (&As)[2][128 * 64], ushort_t (&Bs)[2][128 * 64],
                                             int tid, int lane, int wid, int wr, int wc) {
    int lrow = lane >> 3;
    int sg = (lane & 7) ^ lrow;
    auto issue = [&](int kt, int buf) {
        int kb = k0 + kt * 64;
        for (int i = 0; i < 2; ++i) {
            int rbase = wid * 16 + i * 8;
            gload_lds16(A + (size_t)(m0 + rbase + lrow) * lda + kb + sg * 8, &As[buf][wid * 1024 + i * 512]);
            gload_lds16(Bm + (size_t)(n0 + rbase + lrow) * ldb + kb + sg * 8, &Bs[buf][wid * 1024 + i * 512]);
        }
    };
    issue(0, 0);
    __syncthreads();
    int cur = 0;
    for (int kt = 0; kt < kIters; ++kt) {
        int nxt = cur ^ 1;
        if (kt + 1 < kIters) issue(kt + 1, nxt);
        __builtin_amdgcn_s_setprio(1);
        for (int ks = 0; ks < 2; ++ks) {
            short8 a[4], b[2];
            int sl = ks * 4 + (lane >> 4);
            for (int mi = 0; mi < 4; ++mi) {
                int row = wr * 64 + mi * 16 + (lane & 15);
                a[mi] = *(const short8*)&As[cur][row * 64 + ((sl ^ (row & 7)) << 3)];
            }
            for (int ni = 0; ni < 2; ++ni) {
                int row = wc * 32 + ni * 16 + (lane & 15);
                b[ni] = *(const short8*)&Bs[cur][row * 64 + ((sl ^ (row & 7)) << 3)];
            }
            for (int mi = 0; mi < 4; ++mi)
                for (int ni = 0; ni < 2; ++ni)
                    acc[mi][ni] = __builtin_amdgcn_mfma_f32_16x16x32_bf16(a[mi], b[ni], acc[mi][ni], 0, 0, 0);
        }
        __builtin_amdgcn_s_setprio(0);
        __syncthreads();
        cur = nxt;
    }
}

// ---------------- D1: k_pre_plus: setup(3072) | pack_tw1(32) | transpose_x(256) |
//                      transpose_fw1(4096) | prep1(1); grid 7457 ----------------
__global__ __launch_bounds__(256) void k_pre_plus(const float* __restrict__ x, const float* __restrict__ tw1,
                                                  const float* __restrict__ tw2, const float* __restrict__ fw1,
                                                  const float* __restrict__ emb, const float* __restrict__ w1,
                                                  const float* __restrict__ b1,
                                                  ushort_t* __restrict__ A1cat, ushort_t* __restrict__ B1cat,
                                                  ushort_t* __restrict__ Wt, ushort_t* __restrict__ tw2_bf,
                                                  ushort_t* __restrict__ fw1T,
                                                  float* __restrict__ u_g, int* __restrict__ idxs_g,
                                                  float* __restrict__ bpkey_g) {
    __shared__ float tile[64 * 65];
    __shared__ float key_s[256];
    __shared__ int idx_s[256];
    int bid = blockIdx.x;
    int tid = threadIdx.x;
    if (bid < 3072) {
        int region = bid >> 10;
        int id = ((bid & 1023) << 8) + tid;
        int a = id >> 9, c = id & 511;
        if (region == 0) {       // B1cat rows 0-511: D[t=c][k=a], hi|hi|lo
            int f = (a <= 256) ? a : (a - 256);
            int m = (c * f) & 511;
            float ang = (float)m * (6.283185307179586f / 512.0f);
            float v = ((a <= 256) ? cosf(ang) : -sinf(ang)) * RSQRT512;
            ushort_t hi = f2bf(v);
            ushort_t lo = f2bf(v - bf2f(hi));
            size_t row = (size_t)a * 1536;
            B1cat[row + c] = hi;
            B1cat[row + 512 + c] = hi;
            B1cat[row + 1024 + c] = lo;
        } else if (region == 1) {  // Wt[k=a][t=c]
            int f = (a <= 256) ? a : (a - 256);
            int m = (c * f) & 511;
            float ang = (float)m * (6.283185307179586f / 512.0f);
            float v = ((a <= 256) ? cosf(ang) : -sinf(ang)) * RSQRT512;
            float sc = (a == 0 || a == 256) ? 1.0f : 2.0f;
            Wt[id] = f2bf(v * sc);
        } else {                   // tw2_bf (512 blocks used)
            if ((bid & 1023) < 512) tw2_bf[id] = f2bf(tw2[id]);
        }
    } else if (bid < 3104) {
        // pack_tw1 -> B1cat rows 512-767 (transposed, hi|hi|lo)
        int b = bid - 3072;
        int t0 = (b & 7) << 6, h0 = (b >> 3) << 6;
        float (*t64)[65] = (float(*)[65])tile;
        for (int i = 0; i < 16; ++i) {
            int idx = tid + i * 256;
            int r = idx >> 6, cc = idx & 63;
            t64[r][cc] = tw1[(size_t)(t0 + r) * 256 + h0 + cc];
        }
        __syncthreads();
        for (int i = 0; i < 16; ++i) {
            int idx = tid + i * 256;
            int rr = idx >> 6, cc2 = idx & 63;
            float v = t64[cc2][rr];
            ushort_t hi = f2bf(v);
            ushort_t lo = f2bf(v - bf2f(hi));
            size_t row = (size_t)(512 + h0 + rr) * 1536;
            int t = t0 + cc2;
            B1cat[row + t] = hi;
            B1cat[row + 512 + t] = hi;
            B1cat[row + 1024 + t] = lo;
        }
    } else if (bid < 3360) {
        // transpose_x [8][512][64] -> A1cat [512 bn][1536] (hi|lo|hi)
        int b = bid - 3104;
        int bb = b >> 5;
        int rem = b & 31;
        int t0 = (rem >> 1) << 5;
        int n0 = (rem & 1) << 5;
        int tx = tid & 31, ty = tid >> 5;
        float (*t32)[33] = (float(*)[33])tile;
        for (int i = 0; i < 4; ++i) {
            int tt = ty * 4 + i;
            t32[tt][tx] = x[(size_t)(bb * 512 + t0 + tt) * 64 + n0 + tx];
        }
        __syncthreads();
        for (int i = 0; i < 4; ++i) {
            int nn = ty * 4 + i;
            float v = t32[tx][nn];
            ushort_t hi = f2bf(v);
            ushort_t lo = f2bf(v - bf2f(hi));
            size_t row = (size_t)(bb * 64 + n0 + nn) * 1536;
            int t = t0 + tx;
            A1cat[row + t] = hi;
            A1cat[row + 512 + t] = lo;
            A1cat[row + 1024 + t] = hi;
        }
    } else if (bid < 7456) {
        // transpose_fw1: fw1 [(t,e)][h] f32 -> fw1T[(h*128+e)][t] bf16
        int b = bid - 3360;
        int e  = b & 127;
        int hb = (b >> 7) & 3;
        int tt = b >> 9;
        int t0 = tt << 6, h0 = hb << 6;
        float (*t64)[65] = (float(*)[65])tile;
        for (int i = 0; i < 4; ++i) {
            int idx = tid + i * 256;
            int r = idx >> 4, c4 = idx & 15;
            const float* src = fw1 + ((size_t)(t0 + r) * 128 + e) * 256 + h0 + c4 * 4;
            float4 v = *(const float4*)src;
            t64[r][c4 * 4 + 0] = v.x;
            t64[r][c4 * 4 + 1] = v.y;
            t64[r][c4 * 4 + 2] = v.z;
            t64[r][c4 * 4 + 3] = v.w;
        }
        __syncthreads();
        for (int p = 0; p < 2; ++p) {
            int idx = tid + p * 256;
            int hh = idx >> 3, tg = idx & 7;
            short8 o;
            for (int j = 0; j < 8; ++j) o[j] = (short)f2bf(t64[tg * 8 + j][hh]);
            *(short8*)(fw1T + ((size_t)(h0 + hh) * 128 + e) * 512 + t0 + tg * 8) = o;
        }
    } else {
        // prep1: u = emb@w1, breakpoint keys, bitonic sort
        float acc = 0.f;
#pragma unroll 8
        for (int e = 0; e < 128; ++e) acc += emb[e] * w1[e * 256 + tid];
        u_g[tid] = acc;
        float bb0 = b1[tid];
        key_s[tid] = (acc == 0.f) ? INFINITY : (-bb0 / acc);
        idx_s[tid] = tid;
        __syncthreads();
        for (int k = 2; k <= 256; k <<= 1) {
            for (int j = k >> 1; j > 0; j >>= 1) {
                int ixj = tid ^ j;
                if (ixj > tid) {
                    bool up = ((tid & k) == 0);
                    float a0 = key_s[tid], a1 = key_s[ixj];
                    if ((a0 > a1) == up) {
                        key_s[tid] = a1; key_s[ixj] = a0;
                        int t0 = idx_s[tid]; idx_s[tid] = idx_s[ixj]; idx_s[ixj] = t0;
                    }
                }
                __syncthreads();
            }
        }
        bpkey_g[tid] = key_s[tid];
        idxs_g[tid] = idx_s[tid];
    }
}

// ---------------- D2: k_mid: reduceF(256: reduce_F2+pack_F fused) | prep2(128); grid 384 ----------------
__global__ __launch_bounds__(256) void k_mid(const ushort_t* __restrict__ fw1T, const float* __restrict__ emb,
                                             const float* __restrict__ tb2,
                                             ushort_t* __restrict__ B1cat, ushort_t* __restrict__ F1sbf,
                                             float* __restrict__ p2v,
                                             const float* __restrict__ u_g, const float* __restrict__ b1,
                                             const float* __restrict__ w2, const float* __restrict__ b2,
                                             const int* __restrict__ idxs_g,
                                             ushort_t* __restrict__ Atab, ushort_t* __restrict__ Btab) {
    __shared__ float embs[128];
    __shared__ float red[256];
    __shared__ float sA[256], sB[256];
    int bid = blockIdx.x;
    int tid = threadIdx.x;
    if (bid < 256) {
        int h = bid;
        if (tid < 128) embs[tid] = 1.f + emb[tid];
        __syncthreads();
        int t2 = tid * 2;
        const ushort_t* base = fw1T + ((size_t)h << 16) + t2;
        float as0 = 0.f, as1 = 0.f, ae0 = 0.f, ae1 = 0.f;
#pragma unroll 4
        for (int e = 0; e < 128; ++e) {
            uint v = *(const uint*)(base + (size_t)e * 512);
            float v0 = bf2f((ushort_t)(v & 0xffff));
            float v1 = bf2f((ushort_t)(v >> 16));
            float w = embs[e];
            as0 += v0; as1 += v1;
            ae0 += w * v0; ae1 += w * v1;
        }
        *(uint*)(F1sbf + (size_t)h * 512 + t2) = (uint)f2bf(as0) | ((uint)f2bf(as1) << 16);
        ushort_t hi0 = f2bf(ae0), hi1 = f2bf(ae1);
        ushort_t lo0 = f2bf(ae0 - bf2f(hi0)), lo1 = f2bf(ae1 - bf2f(hi1));
        size_t row = (size_t)(768 + h) * 1536;
        uint hpk = (uint)hi0 | ((uint)hi1 << 16);
        *(uint*)(B1cat + row + t2) = hpk;
        *(uint*)(B1cat + row + 512 + t2) = hpk;
        *(uint*)(B1cat + row + 1024 + t2) = (uint)lo0 | ((uint)lo1 << 16);
        red[tid] = tb2[t2] * as0 + tb2[t2 + 1] * as1;
        __syncthreads();
        for (int off = 128; off > 0; off >>= 1) {
            if (tid < off) red[tid] += red[tid + off];
            __syncthreads();
        }
        if (tid == 0) p2v[h] = red[0];
    } else {
        int e = bid - 256, r = tid;
        float uu0 = u_g[r], bb0 = b1[r];
        float w0 = w2[r * 128 + e];
        float c = (uu0 < 0.f || (uu0 == 0.f && bb0 >= 0.f)) ? 1.0f : 0.01f;
        float bA = c * uu0 * w0, bB = c * bb0 * w0;
        int h = idxs_g[r];
        float uu = u_g[h], bb = b1[h];
        float w = w2[h * 128 + e];
        float sgn = (uu > 0.f) ? 0.99f : -0.99f;
        float dA = sgn * uu * w, dB = sgn * bb * w;
        sA[r] = bA; sB[r] = bB;
        __syncthreads();
        for (int off = 128; off > 0; off >>= 1) {
            if (r < off) { sA[r] += sA[r + off]; sB[r] += sB[r + off]; }
            __syncthreads();
        }
        float baseA = sA[0], baseB = sB[0] + b2[e];
        __syncthreads();
        sA[r] = dA; sB[r] = dB;
        __syncthreads();
        for (int off = 1; off < 256; off <<= 1) {
            float vA = (r >= off) ? sA[r - off] : 0.f;
            float vB = (r >= off) ? sB[r - off] : 0.f;
            __syncthreads();
            sA[r] += vA; sB[r] += vB;
            __syncthreads();
        }
        if (r == 0) { Atab[e] = f2bf(baseA); Btab[e] = f2bf(baseB); }
        Atab[(r + 1) * 128 + e] = f2bf(baseA + sA[r]);
        Btab[(r + 1) * 128 + e] = f2bf(baseB + sB[r]);
    }
}

// ---------------- D3: k_big3: gemm0(1024) | g1(256) | p2(4); grid 1284 @512 thr ----------------
// gemm0: M2T = Wt @ fw1T^T (M=512, N=32768, K=512)
// g1:    partialG[kch] = A1cat @ B1cat^T chunk (M=512, N=1024, K=192/chunk)
// p2:    P2T = (tw2 @ F1s^T)^T (M=N=256, K=512)
__global__ __launch_bounds__(512) void k_big3(const ushort_t* __restrict__ Wt, const ushort_t* __restrict__ fw1T,
                                              ushort_t* __restrict__ M2T,
                                              const ushort_t* __restrict__ A1cat, const ushort_t* __restrict__ B1cat,
                                              float* __restrict__ partialG,
                                              const ushort_t* __restrict__ tw2bf, const ushort_t* __restrict__ F1sbf,
                                              ushort_t* __restrict__ P2T) {
    __shared__ ushort_t As[2][128 * 64];
    __shared__ ushort_t Bs[2][128 * 64];
    int tid = threadIdx.x;
    int lane = tid & 63, wid = tid >> 6;
    int wr = wid >> 2, wc = wid & 3;
    int bid = blockIdx.x;
    f32x4 acc[4][2] = {};
    if (bid < 1024) {
        // gemm0
        int xx = bid & 7, y = bid >> 3;
        int mt = y & 3;
        int nt = ((y >> 2) << 3) | xx;
        int m0 = mt * 128, n0 = nt * 128;
        tile_loop512(Wt, 512, fw1T, 512, m0, n0, 0, 8, acc, As, Bs, tid, lane, wid, wr, wc);
        // epilogue: swizzled LDS stage of 128x128 bf16 C tile, then linear short8 copy
        ushort_t* cstage = &As[0][0];
        for (int mi = 0; mi < 4; ++mi) {
            int ml = wr * 64 + mi * 16 + ((lane >> 4) << 2);
            for (int ni = 0; ni < 2; ++ni) {
                int nl = wc * 32 + ni * 16 + (lane & 15);
                for (int r = 0; r < 4; ++r) {
                    int row = ml + r;
                    cstage[row * 128 + (nl ^ ((row & 7) << 4))] = f2bf(acc[mi][ni][r]);
                }
            }
        }
        __syncthreads();
        short8* d8 = (short8*)(M2T + ((size_t)(n0 >> 7) << 16) + (size_t)m0 * 128);
        for (int i = 0; i < 4; ++i) {
            int p = tid + i * 512;
            int row = p >> 4;
            int col0 = (p & 15) * 8;
            d8[p] = *(const short8*)&cstage[row * 128 + (col0 ^ ((row & 7) << 4))];
        }
    } else if (bid < 1280) {
        // g1 split-K
        int b = bid - 1024;
        int kch = b & 7, tilei = b >> 3;
        int nt = tilei & 7, mt = tilei >> 3;
        int m0 = mt * 128, n0 = nt * 128;
        tile_loop512(A1cat, 1536, B1cat, 1536, m0, n0, kch * 192, 3, acc, As, Bs, tid, lane, wid, wr, wc);
        float* pbase = partialG + (size_t)kch * 524288;
        int mb0 = m0 + wr * 64 + ((lane >> 4) << 2);
        int nb0 = n0 + wc * 32 + (lane & 15);
        for (int mi = 0; mi < 4; ++mi)
            for (int ni = 0; ni < 2; ++ni) {
                int mbase = mb0 + mi * 16;
                int n = nb0 + ni * 16;
                for (int r = 0; r < 4; ++r)
                    pbase[(size_t)(mbase + r) * 1024 + n] = acc[mi][ni][r];
            }
    } else {
        // p2
        int b = bid - 1280;
        int nt = b & 1, mt = b >> 1;
        int m0 = mt * 128, n0 = nt * 128;
        tile_loop512(tw2bf, 512, F1sbf, 512, m0, n0, 0, 8, acc, As, Bs, tid, lane, wid, wr, wc);
        int mb0 = m0 + wr * 64 + ((lane >> 4) << 2);
        int nb0 = n0 + wc * 32 + (lane & 15);
        for (int mi = 0; mi < 4; ++mi)
            for (int ni = 0; ni < 2; ++ni) {
                int mbase = mb0 + mi * 16;
                int n = nb0 + ni * 16;
                ushort4 o;
                o.x = f2bf(acc[mi][ni][0]);
                o.y = f2bf(acc[mi][ni][1]);
                o.z = f2bf(acc[mi][ni][2]);
                o.w = f2bf(acc[mi][ni][3]);
                *(ushort4*)(P2T + (size_t)n * 256 + mbase) = o;
            }
    }
}

// ---------------- D4: GEMM1 (fused): partial[kc] = cook(s) @ M2T^T; s summed from partialG ----------------
// M=512, N=256 (full), K=65536. BM=128, BN=256, split-K 64 chunks of 1024.
// grid 256 = xcd(8) x [kcl(8) x mt(4)]; 8 waves 2x4 (wave tile 64x64).
__global__ __launch_bounds__(512) void k_gemm1(const float* __restrict__ partialG,
                                               const ushort_t* __restrict__ Atab, const ushort_t* __restrict__ Btab,
                                               const float* __restrict__ bpkey,
                                               const ushort_t* __restrict__ Bm,
                                               float* __restrict__ partial) {
    __shared__ ushort_t As[2][128 * 64];     // 32 KB
    __shared__ ushort_t Bs[2][256 * 64];     // 64 KB
    __shared__ float sv_s[1024];
    __shared__ ushort_t r_s[1024];
    __shared__ float bp_s[256];
    int tid = threadIdx.x;
    int lane = tid & 63, wid = tid >> 6;
    int wr = wid >> 2, wc = wid & 3;           // wave tile 64m x 64n
    int bid = blockIdx.x;
    int xcd = bid & 7, j = bid >> 3;
    int kcl = j & 7, mt = j >> 3;
    int kc = xcd * 8 + kcl;
    int m0 = mt * 128;
    int k0 = kc * 1024;
    if (tid < 256) bp_s[tid] = bpkey[tid];
    __syncthreads();
    {   // s-slice = sum of 8 G1 split-K partials (same order as old reduceG1 => bit-identical)
        int row = tid >> 2, j2 = (tid & 3) * 2;
        const float* pg = partialG + (size_t)(m0 + row) * 1024 + kc * 8 + j2;
        for (int q = 0; q < 2; ++q) {
            float sv = 0.f;
#pragma unroll
            for (int kch = 0; kch < 8; ++kch)
                sv += pg[(size_t)kch * 524288 + q];
            int lo = 0, hi = 256;
            while (lo < hi) { int mid = (lo + hi) >> 1; if (bp_s[mid] <= sv) lo = mid + 1; else hi = mid; }
            sv_s[row * 8 + j2 + q] = sv;
            r_s[row * 8 + j2 + q] = (ushort_t)lo;
        }
    }
    __syncthreads();

    int lrow = lane >> 3;
    int sg = (lane & 7) ^ lrow;
    auto issueB = [&](int kt, int buf) {
        int kb = k0 + kt * 64;
        for (int i = 0; i < 4; ++i) {
            int rbase = wid * 32 + i * 8;
            gload_lds16(Bm + (size_t)(rbase + lrow) * 65536 + kb + sg * 8, &Bs[buf][wid * 2048 + i * 512]);
        }
    };
    short8 ta[2], tb[2];
    float svr[2];
    auto gather = [&](int kt) {
        int kl = kt >> 1;
        for (int i = 0; i < 2; ++i) {
            int q = tid + i * 512;
            int row = q >> 3, slot = q & 7;
            int e0 = ((kt & 1) << 6) + slot * 8;
            int r = r_s[row * 8 + kl];
            svr[i] = sv_s[row * 8 + kl];
            ta[i] = *(const short8*)(Atab + r * 128 + e0);
            tb[i] = *(const short8*)(Btab + r * 128 + e0);
        }
    };
    auto cookwrite = [&](int buf) {
        for (int i = 0; i < 2; ++i) {
            int q = tid + i * 512;
            int row = q >> 3, slot = q & 7;
            float sv = svr[i];
            short8 o;
            for (int jj = 0; jj < 8; ++jj) {
                float y = fmaf(sv, bf2f((ushort_t)ta[i][jj]), bf2f((ushort_t)tb[i][jj]));
                y = y - fminf(fmaxf(y, -LAMBDA_), LAMBDA_);
                o[jj] = (short)f2bf_hw(y);
            }
            *(short8*)&As[buf][row * 64 + ((slot ^ (row & 7)) << 3)] = o;
        }
    };

    f32x4 acc[4][4] = {};
    issueB(0, 0);
    gather(0);
    cookwrite(0);
    __syncthreads();
    int cur = 0;
    for (int kt = 0; kt < 16; ++kt) {
        int nxt = cur ^ 1;
        if (kt + 1 < 16) { issueB(kt + 1, nxt); gather(kt + 1); }
        __builtin_amdgcn_s_setprio(1);
        for (int ks = 0; ks < 2; ++ks) {
            short8 a[4], b[4];
            int sl = ks * 4 + (lane >> 4);
            for (int mi = 0; mi < 4; ++mi) {
                int row = wr * 64 + mi * 16 + (lane & 15);
                a[mi] = *(const short8*)&As[cur][row * 64 + ((sl ^ (row & 7)) << 3)];
            }
            for (int ni = 0; ni < 4; ++ni) {
                int row = wc * 64 + ni * 16 + (lane & 15);
                b[ni] = *(const short8*)&Bs[cur][row * 64 + ((sl ^ (row & 7)) << 3)];
            }
            for (int mi = 0; mi < 4; ++mi)
                for (int ni = 0; ni < 4; ++ni)
                    acc[mi][ni] = __builtin_amdgcn_mfma_f32_16x16x32_bf16(a[mi], b[ni], acc[mi][ni], 0, 0, 0);
        }
        __builtin_amdgcn_s_setprio(0);
        if (kt + 1 < 16) cookwrite(nxt);
        __syncthreads();
        cur = nxt;
    }
    int mb0 = m0 + wr * 64 + ((lane >> 4) << 2);
    int nb0 = wc * 64 + (lane & 15);
    float* pbase = partial + (size_t)kc * 131072;
    for (int mi = 0; mi < 4; ++mi)
        for (int ni = 0; ni < 4; ++ni) {
            int mbase = mb0 + mi * 16;
            int n = nb0 + ni * 16;
            for (int r = 0; r < 4; ++r)
                pbase[(size_t)(mbase + r) * 256 + n] = acc[mi][ni][r];
        }
}

// ---------------- D5: k_final: hl/h2c from partialG inline; h2b-row via hl@P2T; out=a@fw2+fb2 ----------------
__global__ __launch_bounds__(128) void k_final(const float* __restrict__ partial, const float* __restrict__ partialG,
                                               const ushort_t* __restrict__ P2T, const float* __restrict__ p2v,
                                               const float* __restrict__ tb1, const float* __restrict__ fb1,
                                               const float* __restrict__ fw2, const float* __restrict__ fb2,
                                               float* __restrict__ out) {
    __shared__ float a_s[256];
    __shared__ float hl_s[256];
    __shared__ float hc_s[256];
    int bn = blockIdx.x;
    int tid = threadIdx.x;
    for (int q = 0; q < 2; ++q) {
        int i = tid * 2 + q;
        float a1 = 0.f, a2 = 0.f;
#pragma unroll
        for (int kch = 0; kch < 8; ++kch) {
            const float* pg = partialG + (size_t)kch * 524288 + (size_t)bn * 1024;
            a1 += pg[512 + i];
            a2 += pg[768 + i];
        }
        hl_s[i] = leaky_(a1 + tb1[i]);      // hl kept in f32 (old path rounded to bf16)
        hc_s[i] = a2;
    }
    __syncthreads();
    for (int p = 0; p < 2; ++p) {
        int i = tid + p * 128;
        float acc = p2v[i] + hc_s[i] + fb1[i];
#pragma unroll 8
        for (int kc = 0; kc < 64; ++kc)
            acc += partial[((size_t)kc * 512 + bn) * 256 + i];
        const ushort_t* prow = P2T + (size_t)i * 256;
#pragma unroll 4
        for (int jb = 0; jb < 32; ++jb) {
            short8 pv = *(const short8*)(prow + jb * 8);
            for (int j8 = 0; j8 < 8; ++j8)
                acc += hl_s[jb * 8 + j8] * bf2f((ushort_t)pv[j8]);
        }
        a_s[i] = leaky_(acc);
    }
    __syncthreads();
    if (tid < 96) {
        float acc = fb2[tid];
        for (int hh = 0; hh < 256; ++hh)
            acc += a_s[hh] * fw2[hh * 96 + tid];
        int b = bn >> 6, n = bn & 63;
        out[(size_t)(b * 96 + tid) * 64 + n] = acc;
    }
}

extern "C" void kernel_launch(void* const* d_in, const int* in_sizes, int n_in,
                              void* d_out, int out_size, void* d_ws, size_t ws_size,
                              hipStream_t stream) {
    const float* x   = (const float*)d_in[0];
    const float* emb = (const float*)d_in[1];
    const float* w1  = (const float*)d_in[2];
    const float* b1  = (const float*)d_in[3];
    const float* w2  = (const float*)d_in[4];
    const float* b2  = (const float*)d_in[5];
    const float* tw1 = (const float*)d_in[6];
    const float* tb1 = (const float*)d_in[7];
    const float* tw2 = (const float*)d_in[8];
    const float* tb2 = (const float*)d_in[9];
    const float* fw1 = (const float*)d_in[10];
    const float* fb1 = (const float*)d_in[11];
    const float* fw2 = (const float*)d_in[12];
    const float* fb2 = (const float*)d_in[13];
    float* out = (float*)d_out;

    char* W = (char*)d_ws;
    size_t off = 0;
    auto take = [&](size_t bytes) { size_t r = off; off += (bytes + 255) & ~(size_t)255; return r; };
    ushort_t* fw1T  = (ushort_t*)(W + take(33554432));        // [32768][512] bf16
    ushort_t* M2T   = (ushort_t*)(W + take(33554432));        // [256 h][65536 k'] bf16
    float* partial  = (float*)(W + take(64 * 512 * 256 * 4)); // [64 kc][512 bn][256 h] f32
    float* partialG = (float*)(W + take(8 * 512 * 1024 * 4)); // [8 kch][512 bn][1024 n] f32
    ushort_t* A1cat = (ushort_t*)(W + take(512 * 1536 * 2));
    ushort_t* B1cat = (ushort_t*)(W + take(1024 * 1536 * 2));
    ushort_t* Wt    = (ushort_t*)(W + take(512 * 512 * 2));
    ushort_t* tw2bf = (ushort_t*)(W + take(256 * 512 * 2));
    ushort_t* F1sbf = (ushort_t*)(W + take(256 * 512 * 2));
    ushort_t* P2T   = (ushort_t*)(W + take(256 * 256 * 2));
    float* p2v      = (float*)(W + take(256 * 4));
    ushort_t* Atab  = (ushort_t*)(W + take(257 * 128 * 2));
    ushort_t* Btab  = (ushort_t*)(W + take(257 * 128 * 2));
    float* bpkey    = (float*)(W + take(256 * 4));
    float* u_g      = (float*)(W + take(256 * 4));
    int* idxs_g     = (int*)(W + take(256 * 4));
    (void)ws_size; (void)in_sizes; (void)n_in; (void)out_size;

    // D1: setup | pack_tw1 | transpose_x | transpose_fw1 | prep1
    k_pre_plus<<<7457, 256, 0, stream>>>(x, tw1, tw2, fw1, emb, w1, b1,
                                         A1cat, B1cat, Wt, tw2bf, fw1T, u_g, idxs_g, bpkey);
    // D2: reduceF (reduce_F2 + pack_F fused) | prep2
    k_mid<<<384, 256, 0, stream>>>(fw1T, emb, tb2, B1cat, F1sbf, p2v,
                                   u_g, b1, w2, b2, idxs_g, Atab, Btab);
    // D3: gemm0 | g1 split-K | p2  (g1/p2 hide under gemm0)
    k_big3<<<1284, 512, 0, stream>>>(Wt, fw1T, M2T, A1cat, B1cat, partialG, tw2bf, F1sbf, P2T);
    // D4: GEMM1 (fused softshrink-A; s summed from partialG in-kernel)
    k_gemm1<<<256, 512, 0, stream>>>(partialG, Atab, Btab, bpkey, M2T, partial);
    // D5: final (hl/h2c from partialG inline)
    k_final<<<512, 128, 0, stream>>>(partial, partialG, P2T, p2v, tb1, fb1, fw2, fb2, out);
}

// Round 15
// 136.316 us; speedup vs baseline: 1.2125x; 1.0080x over previous
//
#include <hip/hip_runtime.h>
#include <hip/hip_bf16.h>

// B=8, T=512, N=64, E=128, H=256, P=96.  bn = b*64+n (512 rows).
// Identities:
//  xe = x_noD*emb  => rfft factorizes: spectral scalar s[bn,k] (packed: k<=256 real, k>256 imag)
//  mlp(s*emb) piecewise-linear in s (257 regions; tables Atab/Btab[r][e])
//  xt-part of flat@fw1:  h2[bn,h] = sum_{k,e} Yp[bn,k,e] * M2[k,e,h],
//      M2[k,(h,e)] = sum_t W[t,k] fw1[(t*128+e)*256+h]   (W = packed irfft basis)
//      Yp values are generated IN-REGISTER inside GEMM1 (fused softshrink), never materialized.
//  xn-part:   xn@F1s = hl@(tw2@F1s) + tb2@F1s,  F1s[t,h] = sum_e fw1
//  bias-part: x_noD@F1e,                        F1e[t,h] = sum_e (1+emb_e) fw1
//  s and x@F1e via hi/lo bf16 K-concat MFMA (A=[hi|lo|hi], B=[hi;hi;lo]) — G1 split-K.
// Round 15: k_gemm1 rebuilt as a 3-buffer pipeline with COUNTED vmcnt waits + raw s_barrier
//  (T3/T4: loads for kt+2 stay in flight across the barrier; no vmcnt(0) drain per K-step).
//  partial -> bf16 (16MB), staged via LDS for full-line stores; k_final reads bf16.

typedef unsigned int uint;
typedef unsigned short ushort_t;
typedef __attribute__((ext_vector_type(4))) float f32x4;
typedef __attribute__((ext_vector_type(8))) short short8;

#define LAMBDA_ 0.001f
#define RSQRT512 0.044194173824159220f

__device__ __forceinline__ ushort_t f2bf(float f) {
    uint u = __float_as_uint(f);
    uint r = (u + 0x7FFFu + ((u >> 16) & 1u)) >> 16;
    return (ushort_t)r;
}
__device__ __forceinline__ ushort_t f2bf_hw(float f) {
    union { __hip_bfloat16 h; ushort_t u; } c;
    c.h = __float2bfloat16(f);
    return c.u;
}
__device__ __forceinline__ float bf2f(ushort_t v) { return __uint_as_float(((uint)v) << 16); }
__device__ __forceinline__ float leaky_(float v) { return v >= 0.f ? v : 0.01f * v; }

__device__ __forceinline__ void gload_lds16(const ushort_t* g, ushort_t* l) {
    __builtin_amdgcn_global_load_lds((const __attribute__((address_space(1))) void*)g,
                                     (__attribute__((address_space(3))) void*)l, 16, 0, 0);
}

// Shared 512-thread 128x128-tile dbuf loop (gload_lds + source-pre-swizzle, 1 barrier/K-step).
__device__ __forceinline__ void tile_loop512(const ushort_t* __restrict__ A, int lda,
                                             const ushort_t* __restrict__ Bm, int ldb,
                                             int m0, int n0, int k0, int kIters,
                                             f32x4 (&acc)[4][2],
                                             ushort_t (&As)[2][128 * 64], ushort_t (&Bs)[2][128 * 64],
                                             int tid, int lane, int wid, int wr, int wc) {
    int lrow = lane >> 3;
    int sg = (lane & 7) ^ lrow;
    auto issue = [&](int kt, int buf) {
        int kb = k0 + kt * 64;
        for (int i = 0; i < 2; ++i) {
            int rbase = wid * 16 + i * 8;
            gload_lds16(A + (size_t)(m0 + rbase + lrow) * lda + kb + sg * 8, &As[buf][wid * 1024 + i * 512]);
            gload_lds16(Bm + (size_t)(n0 + rbase + lrow) * ldb + kb + sg * 8, &Bs[buf][wid * 1024 + i * 512]);
        }
    };
    issue(0, 0);
    __syncthreads();
    int cur = 0;
    for (int kt = 0; kt < kIters; ++kt) {
        int nxt = cur ^ 1;
        if (kt + 1 < kIters) issue(kt + 1, nxt);
        __builtin_amdgcn_s_setprio(1);
        for (int ks = 0; ks < 2; ++ks) {
            short8 a[4], b[2];
            int sl = ks * 4 + (lane >> 4);
            for (int mi = 0; mi < 4; ++mi) {
                int row = wr * 64 + mi * 16 + (lane & 15);
                a[mi] = *(const short8*)&As[cur][row * 64 + ((sl ^ (row & 7)) << 3)];
            }
            for (int ni = 0; ni < 2; ++ni) {
                int row = wc * 32 + ni * 16 + (lane & 15);
                b[ni] = *(const short8*)&Bs[cur][row * 64 + ((sl ^ (row & 7)) << 3)];
            }
            for (int mi = 0; mi < 4; ++mi)
                for (int ni = 0; ni < 2; ++ni)
                    acc[mi][ni] = __builtin_amdgcn_mfma_f32_16x16x32_bf16(a[mi], b[ni], acc[mi][ni], 0, 0, 0);
        }
        __builtin_amdgcn_s_setprio(0);
        __syncthreads();
        cur = nxt;
    }
}

// ---------------- D1: k_pre_plus ----------------
__global__ __launch_bounds__(256) void k_pre_plus(const float* __restrict__ x, const float* __restrict__ tw1,
                                                  const float* __restrict__ tw2, const float* __restrict__ fw1,
                                                  const float* __restrict__ emb, const float* __restrict__ w1,
                                                  const float* __restrict__ b1,
                                                  ushort_t* __restrict__ A1cat, ushort_t* __restrict__ B1cat,
                                                  ushort_t* __restrict__ Wt, ushort_t* __restrict__ tw2_bf,
                                                  ushort_t* __restrict__ fw1T,
                                                  float* __restrict__ u_g, int* __restrict__ idxs_g,
                                                  float* __restrict__ bpkey_g) {
    __shared__ float tile[64 * 65];
    __shared__ float key_s[256];
    __shared__ int idx_s[256];
    int bid = blockIdx.x;
    int tid = threadIdx.x;
    if (bid < 3072) {
        int region = bid >> 10;
        int id = ((bid & 1023) << 8) + tid;
        int a = id >> 9, c = id & 511;
        if (region == 0) {
            int f = (a <= 256) ? a : (a - 256);
            int m = (c * f) & 511;
            float ang = (float)m * (6.283185307179586f / 512.0f);
            float v = ((a <= 256) ? cosf(ang) : -sinf(ang)) * RSQRT512;
            ushort_t hi = f2bf(v);
            ushort_t lo = f2bf(v - bf2f(hi));
            size_t row = (size_t)a * 1536;
            B1cat[row + c] = hi;
            B1cat[row + 512 + c] = hi;
            B1cat[row + 1024 + c] = lo;
        } else if (region == 1) {
            int f = (a <= 256) ? a : (a - 256);
            int m = (c * f) & 511;
            float ang = (float)m * (6.283185307179586f / 512.0f);
            float v = ((a <= 256) ? cosf(ang) : -sinf(ang)) * RSQRT512;
            float sc = (a == 0 || a == 256) ? 1.0f : 2.0f;
            Wt[id] = f2bf(v * sc);
        } else {
            if ((bid & 1023) < 512) tw2_bf[id] = f2bf(tw2[id]);
        }
    } else if (bid < 3104) {
        int b = bid - 3072;
        int t0 = (b & 7) << 6, h0 = (b >> 3) << 6;
        float (*t64)[65] = (float(*)[65])tile;
        for (int i = 0; i < 16; ++i) {
            int idx = tid + i * 256;
            int r = idx >> 6, cc = idx & 63;
            t64[r][cc] = tw1[(size_t)(t0 + r) * 256 + h0 + cc];
        }
        __syncthreads();
        for (int i = 0; i < 16; ++i) {
            int idx = tid + i * 256;
            int rr = idx >> 6, cc2 = idx & 63;
            float v = t64[cc2][rr];
            ushort_t hi = f2bf(v);
            ushort_t lo = f2bf(v - bf2f(hi));
            size_t row = (size_t)(512 + h0 + rr) * 1536;
            int t = t0 + cc2;
            B1cat[row + t] = hi;
            B1cat[row + 512 + t] = hi;
            B1cat[row + 1024 + t] = lo;
        }
    } else if (bid < 3360) {
        int b = bid - 3104;
        int bb = b >> 5;
        int rem = b & 31;
        int t0 = (rem >> 1) << 5;
        int n0 = (rem & 1) << 5;
        int tx = tid & 31, ty = tid >> 5;
        float (*t32)[33] = (float(*)[33])tile;
        for (int i = 0; i < 4; ++i) {
            int tt = ty * 4 + i;
            t32[tt][tx] = x[(size_t)(bb * 512 + t0 + tt) * 64 + n0 + tx];
        }
        __syncthreads();
        for (int i = 0; i < 4; ++i) {
            int nn = ty * 4 + i;
            float v = t32[tx][nn];
            ushort_t hi = f2bf(v);
            ushort_t lo = f2bf(v - bf2f(hi));
            size_t row = (size_t)(bb * 64 + n0 + nn) * 1536;
            int t = t0 + tx;
            A1cat[row + t] = hi;
            A1cat[row + 512 + t] = lo;
            A1cat[row + 1024 + t] = hi;
        }
    } else if (bid < 7456) {
        int b = bid - 3360;
        int e  = b & 127;
        int hb = (b >> 7) & 3;
        int tt = b >> 9;
        int t0 = tt << 6, h0 = hb << 6;
        float (*t64)[65] = (float(*)[65])tile;
        for (int i = 0; i < 4; ++i) {
            int idx = tid + i * 256;
            int r = idx >> 4, c4 = idx & 15;
            const float* src = fw1 + ((size_t)(t0 + r) * 128 + e) * 256 + h0 + c4 * 4;
            float4 v = *(const float4*)src;
            t64[r][c4 * 4 + 0] = v.x;
            t64[r][c4 * 4 + 1] = v.y;
            t64[r][c4 * 4 + 2] = v.z;
            t64[r][c4 * 4 + 3] = v.w;
        }
        __syncthreads();
        for (int p = 0; p < 2; ++p) {
            int idx = tid + p * 256;
            int hh = idx >> 3, tg = idx & 7;
            short8 o;
            for (int j = 0; j < 8; ++j) o[j] = (short)f2bf(t64[tg * 8 + j][hh]);
            *(short8*)(fw1T + ((size_t)(h0 + hh) * 128 + e) * 512 + t0 + tg * 8) = o;
        }
    } else {
        float acc = 0.f;
#pragma unroll 8
        for (int e = 0; e < 128; ++e) acc += emb[e] * w1[e * 256 + tid];
        u_g[tid] = acc;
        float bb0 = b1[tid];
        key_s[tid] = (acc == 0.f) ? INFINITY : (-bb0 / acc);
        idx_s[tid] = tid;
        __syncthreads();
        for (int k = 2; k <= 256; k <<= 1) {
            for (int j = k >> 1; j > 0; j >>= 1) {
                int ixj = tid ^ j;
                if (ixj > tid) {
                    bool up = ((tid & k) == 0);
                    float a0 = key_s[tid], a1 = key_s[ixj];
                    if ((a0 > a1) == up) {
                        key_s[tid] = a1; key_s[ixj] = a0;
                        int t0 = idx_s[tid]; idx_s[tid] = idx_s[ixj]; idx_s[ixj] = t0;
                    }
                }
                __syncthreads();
            }
        }
        bpkey_g[tid] = key_s[tid];
        idxs_g[tid] = idx_s[tid];
    }
}

// ---------------- D2: k_mid ----------------
__global__ __launch_bounds__(256) void k_mid(const ushort_t* __restrict__ fw1T, const float* __restrict__ emb,
                                             const float* __restrict__ tb2,
                                             ushort_t* __restrict__ B1cat, ushort_t* __restrict__ F1sbf,
                                             float* __restrict__ p2v,
                                             const float* __restrict__ u_g, const float* __restrict__ b1,
                                             const float* __restrict__ w2, const float* __restrict__ b2,
                                             const int* __restrict__ idxs_g,
                                             ushort_t* __restrict__ Atab, ushort_t* __restrict__ Btab) {
    __shared__ float embs[128];
    __shared__ float red[256];
    __shared__ float sA[256], sB[256];
    int bid = blockIdx.x;
    int tid = threadIdx.x;
    if (bid < 256) {
        int h = bid;
        if (tid < 128) embs[tid] = 1.f + emb[tid];
        __syncthreads();
        int t2 = tid * 2;
        const ushort_t* base = fw1T + ((size_t)h << 16) + t2;
        float as0 = 0.f, as1 = 0.f, ae0 = 0.f, ae1 = 0.f;
#pragma unroll 4
        for (int e = 0; e < 128; ++e) {
            uint v = *(const uint*)(base + (size_t)e * 512);
            float v0 = bf2f((ushort_t)(v & 0xffff));
            float v1 = bf2f((ushort_t)(v >> 16));
            float w = embs[e];
            as0 += v0; as1 += v1;
            ae0 += w * v0; ae1 += w * v1;
        }
        *(uint*)(F1sbf + (size_t)h * 512 + t2) = (uint)f2bf(as0) | ((uint)f2bf(as1) << 16);
        ushort_t hi0 = f2bf(ae0), hi1 = f2bf(ae1);
        ushort_t lo0 = f2bf(ae0 - bf2f(hi0)), lo1 = f2bf(ae1 - bf2f(hi1));
        size_t row = (size_t)(768 + h) * 1536;
        uint hpk = (uint)hi0 | ((uint)hi1 << 16);
        *(uint*)(B1cat + row + t2) = hpk;
        *(uint*)(B1cat + row + 512 + t2) = hpk;
        *(uint*)(B1cat + row + 1024 + t2) = (uint)lo0 | ((uint)lo1 << 16);
        red[tid] = tb2[t2] * as0 + tb2[t2 + 1] * as1;
        __syncthreads();
        for (int off = 128; off > 0; off >>= 1) {
            if (tid < off) red[tid] += red[tid + off];
            __syncthreads();
        }
        if (tid == 0) p2v[h] = red[0];
    } else {
        int e = bid - 256, r = tid;
        float uu0 = u_g[r], bb0 = b1[r];
        float w0 = w2[r * 128 + e];
        float c = (uu0 < 0.f || (uu0 == 0.f && bb0 >= 0.f)) ? 1.0f : 0.01f;
        float bA = c * uu0 * w0, bB = c * bb0 * w0;
        int h = idxs_g[r];
        float uu = u_g[h], bb = b1[h];
        float w = w2[h * 128 + e];
        float sgn = (uu > 0.f) ? 0.99f : -0.99f;
        float dA = sgn * uu * w, dB = sgn * bb * w;
        sA[r] = bA; sB[r] = bB;
        __syncthreads();
        for (int off = 128; off > 0; off >>= 1) {
            if (r < off) { sA[r] += sA[r + off]; sB[r] += sB[r + off]; }
            __syncthreads();
        }
        float baseA = sA[0], baseB = sB[0] + b2[e];
        __syncthreads();
        sA[r] = dA; sB[r] = dB;
        __syncthreads();
        for (int off = 1; off < 256; off <<= 1) {
            float vA = (r >= off) ? sA[r - off] : 0.f;
            float vB = (r >= off) ? sB[r - off] : 0.f;
            __syncthreads();
            sA[r] += vA; sB[r] += vB;
            __syncthreads();
        }
        if (r == 0) { Atab[e] = f2bf(baseA); Btab[e] = f2bf(baseB); }
        Atab[(r + 1) * 128 + e] = f2bf(baseA + sA[r]);
        Btab[(r + 1) * 128 + e] = f2bf(baseB + sB[r]);
    }
}

// ---------------- D3: k_big3: gemm0(1024) | g1(256) | p2(4); grid 1284 @512 thr ----------------
__global__ __launch_bounds__(512) void k_big3(const ushort_t* __restrict__ Wt, const ushort_t* __restrict__ fw1T,
                                              ushort_t* __restrict__ M2T,
                                              const ushort_t* __restrict__ A1cat, const ushort_t* __restrict__ B1cat,
                                              float* __restrict__ partialG,
                                              const ushort_t* __restrict__ tw2bf, const ushort_t* __restrict__ F1sbf,
                                              ushort_t* __restrict__ P2T) {
    __shared__ ushort_t As[2][128 * 64];
    __shared__ ushort_t Bs[2][128 * 64];
    int tid = threadIdx.x;
    int lane = tid & 63, wid = tid >> 6;
    int wr = wid >> 2, wc = wid & 3;
    int bid = blockIdx.x;
    f32x4 acc[4][2] = {};
    if (bid < 1024) {
        int xx = bid & 7, y = bid >> 3;
        int mt = y & 3;
        int nt = ((y >> 2) << 3) | xx;
        int m0 = mt * 128, n0 = nt * 128;
        tile_loop512(Wt, 512, fw1T, 512, m0, n0, 0, 8, acc, As, Bs, tid, lane, wid, wr, wc);
        ushort_t* cstage = &As[0][0];
        for (int mi = 0; mi < 4; ++mi) {
            int ml = wr * 64 + mi * 16 + ((lane >> 4) << 2);
            for (int ni = 0; ni < 2; ++ni) {
                int nl = wc * 32 + ni * 16 + (lane & 15);
                for (int r = 0; r < 4; ++r) {
                    int row = ml + r;
                    cstage[row * 128 + (nl ^ ((row & 7) << 4))] = f2bf(acc[mi][ni][r]);
                }
            }
        }
        __syncthreads();
        short8* d8 = (short8*)(M2T + ((size_t)(n0 >> 7) << 16) + (size_t)m0 * 128);
        for (int i = 0; i < 4; ++i) {
            int p = tid + i * 512;
            int row = p >> 4;
            int col0 = (p & 15) * 8;
            d8[p] = *(const short8*)&cstage[row * 128 + (col0 ^ ((row & 7) << 4))];
        }
    } else if (bid < 1280) {
        int b = bid - 1024;
        int kch = b & 7, tilei = b >> 3;
        int nt = tilei & 7, mt = tilei >> 3;
        int m0 = mt * 128, n0 = nt * 128;
        tile_loop512(A1cat, 1536, B1cat, 1536, m0, n0, kch * 192, 3, acc, As, Bs, tid, lane, wid, wr, wc);
        float* pbase = partialG + (size_t)kch * 524288;
        int mb0 = m0 + wr * 64 + ((lane >> 4) << 2);
        int nb0 = n0 + wc * 32 + (lane & 15);
        for (int mi = 0; mi < 4; ++mi)
            for (int ni = 0; ni < 2; ++ni) {
                int mbase = mb0 + mi * 16;
                int n = nb0 + ni * 16;
                for (int r = 0; r < 4; ++r)
                    pbase[(size_t)(mbase + r) * 1024 + n] = acc[mi][ni][r];
            }
    } else {
        int b = bid - 1280;
        int nt = b & 1, mt = b >> 1;
        int m0 = mt * 128, n0 = nt * 128;
        tile_loop512(tw2bf, 512, F1sbf, 512, m0, n0, 0, 8, acc, As, Bs, tid, lane, wid, wr, wc);
        int mb0 = m0 + wr * 64 + ((lane >> 4) << 2);
        int nb0 = n0 + wc * 32 + (lane & 15);
        for (int mi = 0; mi < 4; ++mi)
            for (int ni = 0; ni < 2; ++ni) {
                int mbase = mb0 + mi * 16;
                int n = nb0 + ni * 16;
                ushort4 o;
                o.x = f2bf(acc[mi][ni][0]);
                o.y = f2bf(acc[mi][ni][1]);
                o.z = f2bf(acc[mi][ni][2]);
                o.w = f2bf(acc[mi][ni][3]);
                *(ushort4*)(P2T + (size_t)n * 256 + mbase) = o;
            }
    }
}

// ---------------- D4: GEMM1 (fused): 3-buffer pipeline, counted vmcnt, raw barriers ----------------
// M=512, N=256 (full), K=65536. BM=128, BN=256, split-K 64 chunks of 1024 (16 kt of BK=64).
// grid 256 = xcd(8) x [kcl(8) x mt(4)]; 8 waves 2x4 (wave tile 64x64).
// Per iteration kt: issue gathers(kt+2) then B-DMA(kt+2)->buf[(kt+2)%3]; MFMA on buf[kt%3];
// s_waitcnt vmcnt(4) (keeps only B(kt+2) in flight; gathers + B(kt+1) retired);
// cookwrite As[(kt+2)%3]; lgkmcnt(0); raw s_barrier. Buffers read/written disjoint per body.
__global__ __launch_bounds__(512) void k_gemm1(const float* __restrict__ partialG,
                                               const ushort_t* __restrict__ Atab, const ushort_t* __restrict__ Btab,
                                               const float* __restrict__ bpkey,
                                               const ushort_t* __restrict__ Bm,
                                               ushort_t* __restrict__ partial) {
    __shared__ ushort_t As[3][128 * 64];     // 48 KB
    __shared__ ushort_t Bs[3][256 * 64];     // 96 KB
    __shared__ float sv_s[1024];
    __shared__ ushort_t r_s[1024];
    __shared__ float bp_s[256];
    int tid = threadIdx.x;
    int lane = tid & 63, wid = tid >> 6;
    int wr = wid >> 2, wc = wid & 3;           // wave tile 64m x 64n
    int bid = blockIdx.x;
    int xcd = bid & 7, j = bid >> 3;
    int kcl = j & 7, mt = j >> 3;
    int kc = xcd * 8 + kcl;
    int m0 = mt * 128;
    int k0 = kc * 1024;
    if (tid < 256) bp_s[tid] = bpkey[tid];
    __syncthreads();
    {   // s-slice = sum of 8 G1 split-K partials (same order as before => identical values)
        int row = tid >> 2, j2 = (tid & 3) * 2;
        const float* pg = partialG + (size_t)(m0 + row) * 1024 + kc * 8 + j2;
        for (int q = 0; q < 2; ++q) {
            float sv = 0.f;
#pragma unroll
            for (int kch = 0; kch < 8; ++kch)
                sv += pg[(size_t)kch * 524288 + q];
            int lo = 0, hi = 256;
            while (lo < hi) { int mid = (lo + hi) >> 1; if (bp_s[mid] <= sv) lo = mid + 1; else hi = mid; }
            sv_s[row * 8 + j2 + q] = sv;
            r_s[row * 8 + j2 + q] = (ushort_t)lo;
        }
    }
    __syncthreads();

    int lrow = lane >> 3;
    int sg = (lane & 7) ^ lrow;
    auto issueB = [&](int kt, int buf) {       // 4 gload_lds per thread
        int kb = k0 + kt * 64;
        for (int i = 0; i < 4; ++i) {
            int rbase = wid * 32 + i * 8;
            gload_lds16(Bm + (size_t)(rbase + lrow) * 65536 + kb + sg * 8, &Bs[buf][wid * 2048 + i * 512]);
        }
    };
    short8 ta[2], tb[2];
    float svr[2];
    auto gather = [&](int kt) {                // 4 global loads per thread
        int kl = kt >> 1;
        for (int i = 0; i < 2; ++i) {
            int q = tid + i * 512;
            int row = q >> 3, slot = q & 7;
            int e0 = ((kt & 1) << 6) + slot * 8;
            int r = r_s[row * 8 + kl];
            svr[i] = sv_s[row * 8 + kl];
            ta[i] = *(const short8*)(Atab + r * 128 + e0);
            tb[i] = *(const short8*)(Btab + r * 128 + e0);
        }
    };
    auto cookwrite = [&](int buf) {
        for (int i = 0; i < 2; ++i) {
            int q = tid + i * 512;
            int row = q >> 3, slot = q & 7;
            float sv = svr[i];
            short8 o;
            for (int jj = 0; jj < 8; ++jj) {
                float y = fmaf(sv, bf2f((ushort_t)ta[i][jj]), bf2f((ushort_t)tb[i][jj]));
                y = y - fminf(fmaxf(y, -LAMBDA_), LAMBDA_);
                o[jj] = (short)f2bf_hw(y);
            }
            *(short8*)&As[buf][row * 64 + ((slot ^ (row & 7)) << 3)] = o;
        }
    };

    f32x4 acc[4][4] = {};
    // prologue: fill buffers 0 and 1
    gather(0); issueB(0, 0);
    asm volatile("s_waitcnt vmcnt(4)" ::: "memory");   // gathers(0) done; B(0) may fly
    cookwrite(0);
    gather(1); issueB(1, 1);
    asm volatile("s_waitcnt vmcnt(4)" ::: "memory");   // gathers(1)+B(0) done; B(1) flying
    cookwrite(1);
    asm volatile("s_waitcnt lgkmcnt(0)" ::: "memory");
    __builtin_amdgcn_s_barrier();
    __builtin_amdgcn_sched_barrier(0);

    for (int kt = 0; kt < 16; ++kt) {
        int c = kt % 3;
        if (kt + 2 < 16) { gather(kt + 2); issueB(kt + 2, (kt + 2) % 3); }
        __builtin_amdgcn_s_setprio(1);
        for (int ks = 0; ks < 2; ++ks) {
            short8 a[4], b[4];
            int sl = ks * 4 + (lane >> 4);
            for (int mi = 0; mi < 4; ++mi) {
                int row = wr * 64 + mi * 16 + (lane & 15);
                a[mi] = *(const short8*)&As[c][row * 64 + ((sl ^ (row & 7)) << 3)];
            }
            for (int ni = 0; ni < 4; ++ni) {
                int row = wc * 64 + ni * 16 + (lane & 15);
                b[ni] = *(const short8*)&Bs[c][row * 64 + ((sl ^ (row & 7)) << 3)];
            }
            for (int mi = 0; mi < 4; ++mi)
                for (int ni = 0; ni < 4; ++ni)
                    acc[mi][ni] = __builtin_amdgcn_mfma_f32_16x16x32_bf16(a[mi], b[ni], acc[mi][ni], 0, 0, 0);
        }
        __builtin_amdgcn_s_setprio(0);
        if (kt + 2 < 16) {
            asm volatile("s_waitcnt vmcnt(4)" ::: "memory");   // gathers(kt+2)+B(kt+1) done; B(kt+2) flying
            cookwrite((kt + 2) % 3);
        } else {
            asm volatile("s_waitcnt vmcnt(0)" ::: "memory");   // drain tail
        }
        asm volatile("s_waitcnt lgkmcnt(0)" ::: "memory");
        __builtin_amdgcn_s_barrier();
        __builtin_amdgcn_sched_barrier(0);
    }

    // epilogue: stage 128x256 bf16 C tile in Bs[0..1] (64KB linear), then full-line copy
    ushort_t* cstage = &Bs[0][0];
    int mb0l = wr * 64 + ((lane >> 4) << 2);
    int nb0 = wc * 64 + (lane & 15);
    for (int mi = 0; mi < 4; ++mi)
        for (int ni = 0; ni < 4; ++ni) {
            int rowb = mb0l + mi * 16;
            int n = nb0 + ni * 16;
            for (int r = 0; r < 4; ++r)
                cstage[(rowb + r) * 256 + n] = f2bf_hw(acc[mi][ni][r]);
        }
    __syncthreads();
    short8* d8 = (short8*)(partial + (size_t)kc * 131072 + (size_t)m0 * 256);
    const short8* s8 = (const short8*)cstage;
    for (int i = 0; i < 8; ++i) d8[tid + i * 512] = s8[tid + i * 512];
}

// ---------------- D5: k_final: hl/h2c from partialG inline; partial read as bf16 ----------------
__global__ __launch_bounds__(128) void k_final(const ushort_t* __restrict__ partial, const float* __restrict__ partialG,
                                               const ushort_t* __restrict__ P2T, const float* __restrict__ p2v,
                                               const float* __restrict__ tb1, const float* __restrict__ fb1,
                                               const float* __restrict__ fw2, const float* __restrict__ fb2,
                                               float* __restrict__ out) {
    __shared__ float a_s[256];
    __shared__ float hl_s[256];
    __shared__ float hc_s[256];
    int bn = blockIdx.x;
    int tid = threadIdx.x;
    for (int q = 0; q < 2; ++q) {
        int i = tid * 2 + q;
        float a1 = 0.f, a2 = 0.f;
#pragma unroll
        for (int kch = 0; kch < 8; ++kch) {
            const float* pg = partialG + (size_t)kch * 524288 + (size_t)bn * 1024;
            a1 += pg[512 + i];
            a2 += pg[768 + i];
        }
        hl_s[i] = leaky_(a1 + tb1[i]);
        hc_s[i] = a2;
    }
    __syncthreads();
    for (int p = 0; p < 2; ++p) {
        int i = tid + p * 128;
        float acc = p2v[i] + hc_s[i] + fb1[i];
#pragma unroll 8
        for (int kc = 0; kc < 64; ++kc)
            acc += bf2f(partial[((size_t)kc * 512 + bn) * 256 + i]);
        const ushort_t* prow = P2T + (size_t)i * 256;
#pragma unroll 4
        for (int jb = 0; jb < 32; ++jb) {
            short8 pv = *(const short8*)(prow + jb * 8);
            for (int j8 = 0; j8 < 8; ++j8)
                acc += hl_s[jb * 8 + j8] * bf2f((ushort_t)pv[j8]);
        }
        a_s[i] = leaky_(acc);
    }
    __syncthreads();
    if (tid < 96) {
        float acc = fb2[tid];
        for (int hh = 0; hh < 256; ++hh)
            acc += a_s[hh] * fw2[hh * 96 + tid];
        int b = bn >> 6, n = bn & 63;
        out[(size_t)(b * 96 + tid) * 64 + n] = acc;
    }
}

extern "C" void kernel_launch(void* const* d_in, const int* in_sizes, int n_in,
                              void* d_out, int out_size, void* d_ws, size_t ws_size,
                              hipStream_t stream) {
    const float* x   = (const float*)d_in[0];
    const float* emb = (const float*)d_in[1];
    const float* w1  = (const float*)d_in[2];
    const float* b1  = (const float*)d_in[3];
    const float* w2  = (const float*)d_in[4];
    const float* b2  = (const float*)d_in[5];
    const float* tw1 = (const float*)d_in[6];
    const float* tb1 = (const float*)d_in[7];
    const float* tw2 = (const float*)d_in[8];
    const float* tb2 = (const float*)d_in[9];
    const float* fw1 = (const float*)d_in[10];
    const float* fb1 = (const float*)d_in[11];
    const float* fw2 = (const float*)d_in[12];
    const float* fb2 = (const float*)d_in[13];
    float* out = (float*)d_out;

    char* W = (char*)d_ws;
    size_t off = 0;
    auto take = [&](size_t bytes) { size_t r = off; off += (bytes + 255) & ~(size_t)255; return r; };
    ushort_t* fw1T   = (ushort_t*)(W + take(33554432));        // [32768][512] bf16
    ushort_t* M2T    = (ushort_t*)(W + take(33554432));        // [256 h][65536 k'] bf16
    ushort_t* partial= (ushort_t*)(W + take(64 * 512 * 256 * 2)); // [64 kc][512 bn][256 h] bf16
    float* partialG  = (float*)(W + take(8 * 512 * 1024 * 4)); // [8 kch][512 bn][1024 n] f32
    ushort_t* A1cat  = (ushort_t*)(W + take(512 * 1536 * 2));
    ushort_t* B1cat  = (ushort_t*)(W + take(1024 * 1536 * 2));
    ushort_t* Wt     = (ushort_t*)(W + take(512 * 512 * 2));
    ushort_t* tw2bf  = (ushort_t*)(W + take(256 * 512 * 2));
    ushort_t* F1sbf  = (ushort_t*)(W + take(256 * 512 * 2));
    ushort_t* P2T    = (ushort_t*)(W + take(256 * 256 * 2));
    float* p2v       = (float*)(W + take(256 * 4));
    ushort_t* Atab   = (ushort_t*)(W + take(257 * 128 * 2));
    ushort_t* Btab   = (ushort_t*)(W + take(257 * 128 * 2));
    float* bpkey     = (float*)(W + take(256 * 4));
    float* u_g       = (float*)(W + take(256 * 4));
    int* idxs_g      = (int*)(W + take(256 * 4));
    (void)ws_size; (void)in_sizes; (void)n_in; (void)out_size;

    // D1: setup | pack_tw1 | transpose_x | transpose_fw1 | prep1
    k_pre_plus<<<7457, 256, 0, stream>>>(x, tw1, tw2, fw1, emb, w1, b1,
                                         A1cat, B1cat, Wt, tw2bf, fw1T, u_g, idxs_g, bpkey);
    // D2: reduceF | prep2
    k_mid<<<384, 256, 0, stream>>>(fw1T, emb, tb2, B1cat, F1sbf, p2v,
                                   u_g, b1, w2, b2, idxs_g, Atab, Btab);
    // D3: gemm0 | g1 split-K | p2
    k_big3<<<1284, 512, 0, stream>>>(Wt, fw1T, M2T, A1cat, B1cat, partialG, tw2bf, F1sbf, P2T);
    // D4: GEMM1 (fused softshrink-A; 3-buffer counted-vmcnt pipeline; bf16 partial)
    k_gemm1<<<256, 512, 0, stream>>>(partialG, Atab, Btab, bpkey, M2T, partial);
    // D5: final
    k_final<<<512, 128, 0, stream>>>(partial, partialG, P2T, p2v, tb1, fb1, fw2, fb2, out);
}

// Round 16
// 135.962 us; speedup vs baseline: 1.2157x; 1.0026x over previous
//
#include <hip/hip_runtime.h>
#include <hip/hip_bf16.h>

// B=8, T=512, N=64, E=128, H=256, P=96.  bn = b*64+n (512 rows).
// Identities:
//  xe = x_noD*emb  => rfft factorizes: spectral scalar s[bn,k] (packed: k<=256 real, k>256 imag)
//  mlp(s*emb) piecewise-linear in s (257 regions; tables Atab/Btab[r][e])
//  xt-part of flat@fw1:  h2[bn,h] = sum_{k,e} Yp[bn,k,e] * M2[k,e,h],
//      M2[k,(h,e)] = sum_t W[t,k] fw1[(t*128+e)*256+h]   (W = packed irfft basis)
//      Yp values are generated IN-REGISTER inside GEMM1 (fused softshrink), never materialized.
//  xn-part:   xn@F1s = hl@(tw2@F1s) + tb2@F1s,  F1s[t,h] = sum_e fw1
//  bias-part: x_noD@F1e,                        F1e[t,h] = sum_e (1+emb_e) fw1
//  s and x@F1e via hi/lo bf16 K-concat MFMA (A=[hi|lo|hi], B=[hi;hi;lo]) — G1 split-K.
// Round 16: D1 only — hardware __sinf/__cosf (libm range-reduction was the VALU cost),
//  fw1-transpose blocks moved to grid FRONT (memory stream starts at t=0), dead blocks removed.

typedef unsigned int uint;
typedef unsigned short ushort_t;
typedef __attribute__((ext_vector_type(4))) float f32x4;
typedef __attribute__((ext_vector_type(8))) short short8;

#define LAMBDA_ 0.001f
#define RSQRT512 0.044194173824159220f

__device__ __forceinline__ ushort_t f2bf(float f) {
    uint u = __float_as_uint(f);
    uint r = (u + 0x7FFFu + ((u >> 16) & 1u)) >> 16;
    return (ushort_t)r;
}
__device__ __forceinline__ ushort_t f2bf_hw(float f) {
    union { __hip_bfloat16 h; ushort_t u; } c;
    c.h = __float2bfloat16(f);
    return c.u;
}
__device__ __forceinline__ float bf2f(ushort_t v) { return __uint_as_float(((uint)v) << 16); }
__device__ __forceinline__ float leaky_(float v) { return v >= 0.f ? v : 0.01f * v; }

__device__ __forceinline__ void gload_lds16(const ushort_t* g, ushort_t* l) {
    __builtin_amdgcn_global_load_lds((const __attribute__((address_space(1))) void*)g,
                                     (__attribute__((address_space(3))) void*)l, 16, 0, 0);
}

// Shared 512-thread 128x128-tile dbuf loop (gload_lds + source-pre-swizzle, 1 barrier/K-step).
__device__ __forceinline__ void tile_loop512(const ushort_t* __restrict__ A, int lda,
                                             const ushort_t* __restrict__ Bm, int ldb,
                                             int m0, int n0, int k0, int kIters,
                                             f32x4 (&acc)[4][2],
                                             ushort_t (&As)[2][128 * 64], ushort_t (&Bs)[2][128 * 64],
                                             int tid, int lane, int wid, int wr, int wc) {
    int lrow = lane >> 3;
    int sg = (lane & 7) ^ lrow;
    auto issue = [&](int kt, int buf) {
        int kb = k0 + kt * 64;
        for (int i = 0; i < 2; ++i) {
            int rbase = wid * 16 + i * 8;
            gload_lds16(A + (size_t)(m0 + rbase + lrow) * lda + kb + sg * 8, &As[buf][wid * 1024 + i * 512]);
            gload_lds16(Bm + (size_t)(n0 + rbase + lrow) * ldb + kb + sg * 8, &Bs[buf][wid * 1024 + i * 512]);
        }
    };
    issue(0, 0);
    __syncthreads();
    int cur = 0;
    for (int kt = 0; kt < kIters; ++kt) {
        int nxt = cur ^ 1;
        if (kt + 1 < kIters) issue(kt + 1, nxt);
        __builtin_amdgcn_s_setprio(1);
        for (int ks = 0; ks < 2; ++ks) {
            short8 a[4], b[2];
            int sl = ks * 4 + (lane >> 4);
            for (int mi = 0; mi < 4; ++mi) {
                int row = wr * 64 + mi * 16 + (lane & 15);
                a[mi] = *(const short8*)&As[cur][row * 64 + ((sl ^ (row & 7)) << 3)];
            }
            for (int ni = 0; ni < 2; ++ni) {
                int row = wc * 32 + ni * 16 + (lane & 15);
                b[ni] = *(const short8*)&Bs[cur][row * 64 + ((sl ^ (row & 7)) << 3)];
            }
            for (int mi = 0; mi < 4; ++mi)
                for (int ni = 0; ni < 2; ++ni)
                    acc[mi][ni] = __builtin_amdgcn_mfma_f32_16x16x32_bf16(a[mi], b[ni], acc[mi][ni], 0, 0, 0);
        }
        __builtin_amdgcn_s_setprio(0);
        __syncthreads();
        cur = nxt;
    }
}

// ---------------- D1: k_pre_plus (reordered): transpose_fw1[0,4096) | B1cat[4096,5120) |
//                  Wt[5120,6144) | tw2bf[6144,6656) | pack_tw1[6656,6688) |
//                  transpose_x[6688,6944) | prep1{6944}; grid 6945 ----------------
__global__ __launch_bounds__(256) void k_pre_plus(const float* __restrict__ x, const float* __restrict__ tw1,
                                                  const float* __restrict__ tw2, const float* __restrict__ fw1,
                                                  const float* __restrict__ emb, const float* __restrict__ w1,
                                                  const float* __restrict__ b1,
                                                  ushort_t* __restrict__ A1cat, ushort_t* __restrict__ B1cat,
                                                  ushort_t* __restrict__ Wt, ushort_t* __restrict__ tw2_bf,
                                                  ushort_t* __restrict__ fw1T,
                                                  float* __restrict__ u_g, int* __restrict__ idxs_g,
                                                  float* __restrict__ bpkey_g) {
    __shared__ float tile[64 * 65];
    __shared__ float key_s[256];
    __shared__ int idx_s[256];
    int bid = blockIdx.x;
    int tid = threadIdx.x;
    if (bid < 4096) {
        // transpose_fw1: fw1 [(t,e)][h] f32 -> fw1T[(h*128+e)][t] bf16  (memory stream first)
        int b = bid;
        int e  = b & 127;
        int hb = (b >> 7) & 3;
        int tt = b >> 9;
        int t0 = tt << 6, h0 = hb << 6;
        float (*t64)[65] = (float(*)[65])tile;
        for (int i = 0; i < 4; ++i) {
            int idx = tid + i * 256;
            int r = idx >> 4, c4 = idx & 15;
            const float* src = fw1 + ((size_t)(t0 + r) * 128 + e) * 256 + h0 + c4 * 4;
            float4 v = *(const float4*)src;
            t64[r][c4 * 4 + 0] = v.x;
            t64[r][c4 * 4 + 1] = v.y;
            t64[r][c4 * 4 + 2] = v.z;
            t64[r][c4 * 4 + 3] = v.w;
        }
        __syncthreads();
        for (int p = 0; p < 2; ++p) {
            int idx = tid + p * 256;
            int hh = idx >> 3, tg = idx & 7;
            short8 o;
            for (int j = 0; j < 8; ++j) o[j] = (short)f2bf(t64[tg * 8 + j][hh]);
            *(short8*)(fw1T + ((size_t)(h0 + hh) * 128 + e) * 512 + t0 + tg * 8) = o;
        }
    } else if (bid < 5120) {
        // B1cat rows 0-511: D[t=c][k=a], hi|hi|lo  (hardware trig)
        int id = ((bid - 4096) << 8) + tid;
        int a = id >> 9, c = id & 511;
        int f = (a <= 256) ? a : (a - 256);
        int m = (c * f) & 511;
        float ang = (float)m * (6.283185307179586f / 512.0f);
        float v = ((a <= 256) ? __cosf(ang) : -__sinf(ang)) * RSQRT512;
        ushort_t hi = f2bf(v);
        ushort_t lo = f2bf(v - bf2f(hi));
        size_t row = (size_t)a * 1536;
        B1cat[row + c] = hi;
        B1cat[row + 512 + c] = hi;
        B1cat[row + 1024 + c] = lo;
    } else if (bid < 6144) {
        // Wt[k=a][t=c]  (hardware trig)
        int id = ((bid - 5120) << 8) + tid;
        int a = id >> 9, c = id & 511;
        int f = (a <= 256) ? a : (a - 256);
        int m = (c * f) & 511;
        float ang = (float)m * (6.283185307179586f / 512.0f);
        float v = ((a <= 256) ? __cosf(ang) : -__sinf(ang)) * RSQRT512;
        float sc = (a == 0 || a == 256) ? 1.0f : 2.0f;
        Wt[id] = f2bf(v * sc);
    } else if (bid < 6656) {
        // tw2_bf (512 blocks exactly)
        int id = ((bid - 6144) << 8) + tid;
        tw2_bf[id] = f2bf(tw2[id]);
    } else if (bid < 6688) {
        // pack_tw1 -> B1cat rows 512-767 (transposed, hi|hi|lo)
        int b = bid - 6656;
        int t0 = (b & 7) << 6, h0 = (b >> 3) << 6;
        float (*t64)[65] = (float(*)[65])tile;
        for (int i = 0; i < 16; ++i) {
            int idx = tid + i * 256;
            int r = idx >> 6, cc = idx & 63;
            t64[r][cc] = tw1[(size_t)(t0 + r) * 256 + h0 + cc];
        }
        __syncthreads();
        for (int i = 0; i < 16; ++i) {
            int idx = tid + i * 256;
            int rr = idx >> 6, cc2 = idx & 63;
            float v = t64[cc2][rr];
            ushort_t hi = f2bf(v);
            ushort_t lo = f2bf(v - bf2f(hi));
            size_t row = (size_t)(512 + h0 + rr) * 1536;
            int t = t0 + cc2;
            B1cat[row + t] = hi;
            B1cat[row + 512 + t] = hi;
            B1cat[row + 1024 + t] = lo;
        }
    } else if (bid < 6944) {
        // transpose_x [8][512][64] -> A1cat [512 bn][1536] (hi|lo|hi)
        int b = bid - 6688;
        int bb = b >> 5;
        int rem = b & 31;
        int t0 = (rem >> 1) << 5;
        int n0 = (rem & 1) << 5;
        int tx = tid & 31, ty = tid >> 5;
        float (*t32)[33] = (float(*)[33])tile;
        for (int i = 0; i < 4; ++i) {
            int tt = ty * 4 + i;
            t32[tt][tx] = x[(size_t)(bb * 512 + t0 + tt) * 64 + n0 + tx];
        }
        __syncthreads();
        for (int i = 0; i < 4; ++i) {
            int nn = ty * 4 + i;
            float v = t32[tx][nn];
            ushort_t hi = f2bf(v);
            ushort_t lo = f2bf(v - bf2f(hi));
            size_t row = (size_t)(bb * 64 + n0 + nn) * 1536;
            int t = t0 + tx;
            A1cat[row + t] = hi;
            A1cat[row + 512 + t] = lo;
            A1cat[row + 1024 + t] = hi;
        }
    } else {
        // prep1: u = emb@w1, breakpoint keys, bitonic sort
        float acc = 0.f;
#pragma unroll 8
        for (int e = 0; e < 128; ++e) acc += emb[e] * w1[e * 256 + tid];
        u_g[tid] = acc;
        float bb0 = b1[tid];
        key_s[tid] = (acc == 0.f) ? INFINITY : (-bb0 / acc);
        idx_s[tid] = tid;
        __syncthreads();
        for (int k = 2; k <= 256; k <<= 1) {
            for (int j = k >> 1; j > 0; j >>= 1) {
                int ixj = tid ^ j;
                if (ixj > tid) {
                    bool up = ((tid & k) == 0);
                    float a0 = key_s[tid], a1 = key_s[ixj];
                    if ((a0 > a1) == up) {
                        key_s[tid] = a1; key_s[ixj] = a0;
                        int t0 = idx_s[tid]; idx_s[tid] = idx_s[ixj]; idx_s[ixj] = t0;
                    }
                }
                __syncthreads();
            }
        }
        bpkey_g[tid] = key_s[tid];
        idxs_g[tid] = idx_s[tid];
    }
}

// ---------------- D2: k_mid ----------------
__global__ __launch_bounds__(256) void k_mid(const ushort_t* __restrict__ fw1T, const float* __restrict__ emb,
                                             const float* __restrict__ tb2,
                                             ushort_t* __restrict__ B1cat, ushort_t* __restrict__ F1sbf,
                                             float* __restrict__ p2v,
                                             const float* __restrict__ u_g, const float* __restrict__ b1,
                                             const float* __restrict__ w2, const float* __restrict__ b2,
                                             const int* __restrict__ idxs_g,
                                             ushort_t* __restrict__ Atab, ushort_t* __restrict__ Btab) {
    __shared__ float embs[128];
    __shared__ float red[256];
    __shared__ float sA[256], sB[256];
    int bid = blockIdx.x;
    int tid = threadIdx.x;
    if (bid < 256) {
        int h = bid;
        if (tid < 128) embs[tid] = 1.f + emb[tid];
        __syncthreads();
        int t2 = tid * 2;
        const ushort_t* base = fw1T + ((size_t)h << 16) + t2;
        float as0 = 0.f, as1 = 0.f, ae0 = 0.f, ae1 = 0.f;
#pragma unroll 4
        for (int e = 0; e < 128; ++e) {
            uint v = *(const uint*)(base + (size_t)e * 512);
            float v0 = bf2f((ushort_t)(v & 0xffff));
            float v1 = bf2f((ushort_t)(v >> 16));
            float w = embs[e];
            as0 += v0; as1 += v1;
            ae0 += w * v0; ae1 += w * v1;
        }
        *(uint*)(F1sbf + (size_t)h * 512 + t2) = (uint)f2bf(as0) | ((uint)f2bf(as1) << 16);
        ushort_t hi0 = f2bf(ae0), hi1 = f2bf(ae1);
        ushort_t lo0 = f2bf(ae0 - bf2f(hi0)), lo1 = f2bf(ae1 - bf2f(hi1));
        size_t row = (size_t)(768 + h) * 1536;
        uint hpk = (uint)hi0 | ((uint)hi1 << 16);
        *(uint*)(B1cat + row + t2) = hpk;
        *(uint*)(B1cat + row + 512 + t2) = hpk;
        *(uint*)(B1cat + row + 1024 + t2) = (uint)lo0 | ((uint)lo1 << 16);
        red[tid] = tb2[t2] * as0 + tb2[t2 + 1] * as1;
        __syncthreads();
        for (int off = 128; off > 0; off >>= 1) {
            if (tid < off) red[tid] += red[tid + off];
            __syncthreads();
        }
        if (tid == 0) p2v[h] = red[0];
    } else {
        int e = bid - 256, r = tid;
        float uu0 = u_g[r], bb0 = b1[r];
        float w0 = w2[r * 128 + e];
        float c = (uu0 < 0.f || (uu0 == 0.f && bb0 >= 0.f)) ? 1.0f : 0.01f;
        float bA = c * uu0 * w0, bB = c * bb0 * w0;
        int h = idxs_g[r];
        float uu = u_g[h], bb = b1[h];
        float w = w2[h * 128 + e];
        float sgn = (uu > 0.f) ? 0.99f : -0.99f;
        float dA = sgn * uu * w, dB = sgn * bb * w;
        sA[r] = bA; sB[r] = bB;
        __syncthreads();
        for (int off = 128; off > 0; off >>= 1) {
            if (r < off) { sA[r] += sA[r + off]; sB[r] += sB[r + off]; }
            __syncthreads();
        }
        float baseA = sA[0], baseB = sB[0] + b2[e];
        __syncthreads();
        sA[r] = dA; sB[r] = dB;
        __syncthreads();
        for (int off = 1; off < 256; off <<= 1) {
            float vA = (r >= off) ? sA[r - off] : 0.f;
            float vB = (r >= off) ? sB[r - off] : 0.f;
            __syncthreads();
            sA[r] += vA; sB[r] += vB;
            __syncthreads();
        }
        if (r == 0) { Atab[e] = f2bf(baseA); Btab[e] = f2bf(baseB); }
        Atab[(r + 1) * 128 + e] = f2bf(baseA + sA[r]);
        Btab[(r + 1) * 128 + e] = f2bf(baseB + sB[r]);
    }
}

// ---------------- D3: k_big3: gemm0(1024) | g1(256) | p2(4); grid 1284 @512 thr ----------------
__global__ __launch_bounds__(512) void k_big3(const ushort_t* __restrict__ Wt, const ushort_t* __restrict__ fw1T,
                                              ushort_t* __restrict__ M2T,
                                              const ushort_t* __restrict__ A1cat, const ushort_t* __restrict__ B1cat,
                                              float* __restrict__ partialG,
                                              const ushort_t* __restrict__ tw2bf, const ushort_t* __restrict__ F1sbf,
                                              ushort_t* __restrict__ P2T) {
    __shared__ ushort_t As[2][128 * 64];
    __shared__ ushort_t Bs[2][128 * 64];
    int tid = threadIdx.x;
    int lane = tid & 63, wid = tid >> 6;
    int wr = wid >> 2, wc = wid & 3;
    int bid = blockIdx.x;
    f32x4 acc[4][2] = {};
    if (bid < 1024) {
        int xx = bid & 7, y = bid >> 3;
        int mt = y & 3;
        int nt = ((y >> 2) << 3) | xx;
        int m0 = mt * 128, n0 = nt * 128;
        tile_loop512(Wt, 512, fw1T, 512, m0, n0, 0, 8, acc, As, Bs, tid, lane, wid, wr, wc);
        ushort_t* cstage = &As[0][0];
        for (int mi = 0; mi < 4; ++mi) {
            int ml = wr * 64 + mi * 16 + ((lane >> 4) << 2);
            for (int ni = 0; ni < 2; ++ni) {
                int nl = wc * 32 + ni * 16 + (lane & 15);
                for (int r = 0; r < 4; ++r) {
                    int row = ml + r;
                    cstage[row * 128 + (nl ^ ((row & 7) << 4))] = f2bf(acc[mi][ni][r]);
                }
            }
        }
        __syncthreads();
        short8* d8 = (short8*)(M2T + ((size_t)(n0 >> 7) << 16) + (size_t)m0 * 128);
        for (int i = 0; i < 4; ++i) {
            int p = tid + i * 512;
            int row = p >> 4;
            int col0 = (p & 15) * 8;
            d8[p] = *(const short8*)&cstage[row * 128 + (col0 ^ ((row & 7) << 4))];
        }
    } else if (bid < 1280) {
        int b = bid - 1024;
        int kch = b & 7, tilei = b >> 3;
        int nt = tilei & 7, mt = tilei >> 3;
        int m0 = mt * 128, n0 = nt * 128;
        tile_loop512(A1cat, 1536, B1cat, 1536, m0, n0, kch * 192, 3, acc, As, Bs, tid, lane, wid, wr, wc);
        float* pbase = partialG + (size_t)kch * 524288;
        int mb0 = m0 + wr * 64 + ((lane >> 4) << 2);
        int nb0 = n0 + wc * 32 + (lane & 15);
        for (int mi = 0; mi < 4; ++mi)
            for (int ni = 0; ni < 2; ++ni) {
                int mbase = mb0 + mi * 16;
                int n = nb0 + ni * 16;
                for (int r = 0; r < 4; ++r)
                    pbase[(size_t)(mbase + r) * 1024 + n] = acc[mi][ni][r];
            }
    } else {
        int b = bid - 1280;
        int nt = b & 1, mt = b >> 1;
        int m0 = mt * 128, n0 = nt * 128;
        tile_loop512(tw2bf, 512, F1sbf, 512, m0, n0, 0, 8, acc, As, Bs, tid, lane, wid, wr, wc);
        int mb0 = m0 + wr * 64 + ((lane >> 4) << 2);
        int nb0 = n0 + wc * 32 + (lane & 15);
        for (int mi = 0; mi < 4; ++mi)
            for (int ni = 0; ni < 2; ++ni) {
                int mbase = mb0 + mi * 16;
                int n = nb0 + ni * 16;
                ushort4 o;
                o.x = f2bf(acc[mi][ni][0]);
                o.y = f2bf(acc[mi][ni][1]);
                o.z = f2bf(acc[mi][ni][2]);
                o.w = f2bf(acc[mi][ni][3]);
                *(ushort4*)(P2T + (size_t)n * 256 + mbase) = o;
            }
    }
}

// ---------------- D4: GEMM1 (fused): 3-buffer pipeline, counted vmcnt, raw barriers ----------------
__global__ __launch_bounds__(512) void k_gemm1(const float* __restrict__ partialG,
                                               const ushort_t* __restrict__ Atab, const ushort_t* __restrict__ Btab,
                                               const float* __restrict__ bpkey,
                                               const ushort_t* __restrict__ Bm,
                                               ushort_t* __restrict__ partial) {
    __shared__ ushort_t As[3][128 * 64];     // 48 KB
    __shared__ ushort_t Bs[3][256 * 64];     // 96 KB
    __shared__ float sv_s[1024];
    __shared__ ushort_t r_s[1024];
    __shared__ float bp_s[256];
    int tid = threadIdx.x;
    int lane = tid & 63, wid = tid >> 6;
    int wr = wid >> 2, wc = wid & 3;           // wave tile 64m x 64n
    int bid = blockIdx.x;
    int xcd = bid & 7, j = bid >> 3;
    int kcl = j & 7, mt = j >> 3;
    int kc = xcd * 8 + kcl;
    int m0 = mt * 128;
    int k0 = kc * 1024;
    if (tid < 256) bp_s[tid] = bpkey[tid];
    __syncthreads();
    {   // s-slice = sum of 8 G1 split-K partials
        int row = tid >> 2, j2 = (tid & 3) * 2;
        const float* pg = partialG + (size_t)(m0 + row) * 1024 + kc * 8 + j2;
        for (int q = 0; q < 2; ++q) {
            float sv = 0.f;
#pragma unroll
            for (int kch = 0; kch < 8; ++kch)
                sv += pg[(size_t)kch * 524288 + q];
            int lo = 0, hi = 256;
            while (lo < hi) { int mid = (lo + hi) >> 1; if (bp_s[mid] <= sv) lo = mid + 1; else hi = mid; }
            sv_s[row * 8 + j2 + q] = sv;
            r_s[row * 8 + j2 + q] = (ushort_t)lo;
        }
    }
    __syncthreads();

    int lrow = lane >> 3;
    int sg = (lane & 7) ^ lrow;
    auto issueB = [&](int kt, int buf) {
        int kb = k0 + kt * 64;
        for (int i = 0; i < 4; ++i) {
            int rbase = wid * 32 + i * 8;
            gload_lds16(Bm + (size_t)(rbase + lrow) * 65536 + kb + sg * 8, &Bs[buf][wid * 2048 + i * 512]);
        }
    };
    short8 ta[2], tb[2];
    float svr[2];
    auto gather = [&](int kt) {
        int kl = kt >> 1;
        for (int i = 0; i < 2; ++i) {
            int q = tid + i * 512;
            int row = q >> 3, slot = q & 7;
            int e0 = ((kt & 1) << 6) + slot * 8;
            int r = r_s[row * 8 + kl];
            svr[i] = sv_s[row * 8 + kl];
            ta[i] = *(const short8*)(Atab + r * 128 + e0);
            tb[i] = *(const short8*)(Btab + r * 128 + e0);
        }
    };
    auto cookwrite = [&](int buf) {
        for (int i = 0; i < 2; ++i) {
            int q = tid + i * 512;
            int row = q >> 3, slot = q & 7;
            float sv = svr[i];
            short8 o;
            for (int jj = 0; jj < 8; ++jj) {
                float y = fmaf(sv, bf2f((ushort_t)ta[i][jj]), bf2f((ushort_t)tb[i][jj]));
                y = y - fminf(fmaxf(y, -LAMBDA_), LAMBDA_);
                o[jj] = (short)f2bf_hw(y);
            }
            *(short8*)&As[buf][row * 64 + ((slot ^ (row & 7)) << 3)] = o;
        }
    };

    f32x4 acc[4][4] = {};
    gather(0); issueB(0, 0);
    asm volatile("s_waitcnt vmcnt(4)" ::: "memory");
    cookwrite(0);
    gather(1); issueB(1, 1);
    asm volatile("s_waitcnt vmcnt(4)" ::: "memory");
    cookwrite(1);
    asm volatile("s_waitcnt lgkmcnt(0)" ::: "memory");
    __builtin_amdgcn_s_barrier();
    __builtin_amdgcn_sched_barrier(0);

    for (int kt = 0; kt < 16; ++kt) {
        int c = kt % 3;
        if (kt + 2 < 16) { gather(kt + 2); issueB(kt + 2, (kt + 2) % 3); }
        __builtin_amdgcn_s_setprio(1);
        for (int ks = 0; ks < 2; ++ks) {
            short8 a[4], b[4];
            int sl = ks * 4 + (lane >> 4);
            for (int mi = 0; mi < 4; ++mi) {
                int row = wr * 64 + mi * 16 + (lane & 15);
                a[mi] = *(const short8*)&As[c][row * 64 + ((sl ^ (row & 7)) << 3)];
            }
            for (int ni = 0; ni < 4; ++ni) {
                int row = wc * 64 + ni * 16 + (lane & 15);
                b[ni] = *(const short8*)&Bs[c][row * 64 + ((sl ^ (row & 7)) << 3)];
            }
            for (int mi = 0; mi < 4; ++mi)
                for (int ni = 0; ni < 4; ++ni)
                    acc[mi][ni] = __builtin_amdgcn_mfma_f32_16x16x32_bf16(a[mi], b[ni], acc[mi][ni], 0, 0, 0);
        }
        __builtin_amdgcn_s_setprio(0);
        if (kt + 2 < 16) {
            asm volatile("s_waitcnt vmcnt(4)" ::: "memory");
            cookwrite((kt + 2) % 3);
        } else {
            asm volatile("s_waitcnt vmcnt(0)" ::: "memory");
        }
        asm volatile("s_waitcnt lgkmcnt(0)" ::: "memory");
        __builtin_amdgcn_s_barrier();
        __builtin_amdgcn_sched_barrier(0);
    }

    ushort_t* cstage = &Bs[0][0];
    int mb0l = wr * 64 + ((lane >> 4) << 2);
    int nb0 = wc * 64 + (lane & 15);
    for (int mi = 0; mi < 4; ++mi)
        for (int ni = 0; ni < 4; ++ni) {
            int rowb = mb0l + mi * 16;
            int n = nb0 + ni * 16;
            for (int r = 0; r < 4; ++r)
                cstage[(rowb + r) * 256 + n] = f2bf_hw(acc[mi][ni][r]);
        }
    __syncthreads();
    short8* d8 = (short8*)(partial + (size_t)kc * 131072 + (size_t)m0 * 256);
    const short8* s8 = (const short8*)cstage;
    for (int i = 0; i < 8; ++i) d8[tid + i * 512] = s8[tid + i * 512];
}

// ---------------- D5: k_final ----------------
__global__ __launch_bounds__(128) void k_final(const ushort_t* __restrict__ partial, const float* __restrict__ partialG,
                                               const ushort_t* __restrict__ P2T, const float* __restrict__ p2v,
                                               const float* __restrict__ tb1, const float* __restrict__ fb1,
                                               const float* __restrict__ fw2, const float* __restrict__ fb2,
                                               float* __restrict__ out) {
    __shared__ float a_s[256];
    __shared__ float hl_s[256];
    __shared__ float hc_s[256];
    int bn = blockIdx.x;
    int tid = threadIdx.x;
    for (int q = 0; q < 2; ++q) {
        int i = tid * 2 + q;
        float a1 = 0.f, a2 = 0.f;
#pragma unroll
        for (int kch = 0; kch < 8; ++kch) {
            const float* pg = partialG + (size_t)kch * 524288 + (size_t)bn * 1024;
            a1 += pg[512 + i];
            a2 += pg[768 + i];
        }
        hl_s[i] = leaky_(a1 + tb1[i]);
        hc_s[i] = a2;
    }
    __syncthreads();
    for (int p = 0; p < 2; ++p) {
        int i = tid + p * 128;
        float acc = p2v[i] + hc_s[i] + fb1[i];
#pragma unroll 8
        for (int kc = 0; kc < 64; ++kc)
            acc += bf2f(partial[((size_t)kc * 512 + bn) * 256 + i]);
        const ushort_t* prow = P2T + (size_t)i * 256;
#pragma unroll 4
        for (int jb = 0; jb < 32; ++jb) {
            short8 pv = *(const short8*)(prow + jb * 8);
            for (int j8 = 0; j8 < 8; ++j8)
                acc += hl_s[jb * 8 + j8] * bf2f((ushort_t)pv[j8]);
        }
        a_s[i] = leaky_(acc);
    }
    __syncthreads();
    if (tid < 96) {
        float acc = fb2[tid];
        for (int hh = 0; hh < 256; ++hh)
            acc += a_s[hh] * fw2[hh * 96 + tid];
        int b = bn >> 6, n = bn & 63;
        out[(size_t)(b * 96 + tid) * 64 + n] = acc;
    }
}

extern "C" void kernel_launch(void* const* d_in, const int* in_sizes, int n_in,
                              void* d_out, int out_size, void* d_ws, size_t ws_size,
                              hipStream_t stream) {
    const float* x   = (const float*)d_in[0];
    const float* emb = (const float*)d_in[1];
    const float* w1  = (const float*)d_in[2];
    const float* b1  = (const float*)d_in[3];
    const float* w2  = (const float*)d_in[4];
    const float* b2  = (const float*)d_in[5];
    const float* tw1 = (const float*)d_in[6];
    const float* tb1 = (const float*)d_in[7];
    const float* tw2 = (const float*)d_in[8];
    const float* tb2 = (const float*)d_in[9];
    const float* fw1 = (const float*)d_in[10];
    const float* fb1 = (const float*)d_in[11];
    const float* fw2 = (const float*)d_in[12];
    const float* fb2 = (const float*)d_in[13];
    float* out = (float*)d_out;

    char* W = (char*)d_ws;
    size_t off = 0;
    auto take = [&](size_t bytes) { size_t r = off; off += (bytes + 255) & ~(size_t)255; return r; };
    ushort_t* fw1T   = (ushort_t*)(W + take(33554432));        // [32768][512] bf16
    ushort_t* M2T    = (ushort_t*)(W + take(33554432));        // [256 h][65536 k'] bf16
    ushort_t* partial= (ushort_t*)(W + take(64 * 512 * 256 * 2)); // [64 kc][512 bn][256 h] bf16
    float* partialG  = (float*)(W + take(8 * 512 * 1024 * 4)); // [8 kch][512 bn][1024 n] f32
    ushort_t* A1cat  = (ushort_t*)(W + take(512 * 1536 * 2));
    ushort_t* B1cat  = (ushort_t*)(W + take(1024 * 1536 * 2));
    ushort_t* Wt     = (ushort_t*)(W + take(512 * 512 * 2));
    ushort_t* tw2bf  = (ushort_t*)(W + take(256 * 512 * 2));
    ushort_t* F1sbf  = (ushort_t*)(W + take(256 * 512 * 2));
    ushort_t* P2T    = (ushort_t*)(W + take(256 * 256 * 2));
    float* p2v       = (float*)(W + take(256 * 4));
    ushort_t* Atab   = (ushort_t*)(W + take(257 * 128 * 2));
    ushort_t* Btab   = (ushort_t*)(W + take(257 * 128 * 2));
    float* bpkey     = (float*)(W + take(256 * 4));
    float* u_g       = (float*)(W + take(256 * 4));
    int* idxs_g      = (int*)(W + take(256 * 4));
    (void)ws_size; (void)in_sizes; (void)n_in; (void)out_size;

    // D1: transpose_fw1 (front) | B1cat | Wt | tw2bf | pack_tw1 | transpose_x | prep1
    k_pre_plus<<<6945, 256, 0, stream>>>(x, tw1, tw2, fw1, emb, w1, b1,
                                         A1cat, B1cat, Wt, tw2bf, fw1T, u_g, idxs_g, bpkey);
    // D2: reduceF | prep2
    k_mid<<<384, 256, 0, stream>>>(fw1T, emb, tb2, B1cat, F1sbf, p2v,
                                   u_g, b1, w2, b2, idxs_g, Atab, Btab);
    // D3: gemm0 | g1 split-K | p2
    k_big3<<<1284, 512, 0, stream>>>(Wt, fw1T, M2T, A1cat, B1cat, partialG, tw2bf, F1sbf, P2T);
    // D4: GEMM1 (fused softshrink-A; 3-buffer counted-vmcnt pipeline; bf16 partial)
    k_gemm1<<<256, 512, 0, stream>>>(partialG, Atab, Btab, bpkey, M2T, partial);
    // D5: final
    k_final<<<512, 128, 0, stream>>>(partial, partialG, P2T, p2v, tb1, fb1, fw2, fb2, out);
}